// Round 15
// baseline (62.250 us; speedup 1.0000x reference)
//
#include <hip/hip_runtime.h>

// Banded-block sparse attention, B=4, S=4096, D=128, block=64, w=32.
// Masked scores are 0 (not -inf) -> closed-form out-of-band correction.
//
// R15 = R12 (best verified: raw-2^S bf16-P softmax, V-in-LDS, 2 tiles per
// barrier period, pair-wg) with CHUNKS 8 -> 4:
//  - PART halves (34.6 -> 17.3 MB): attn stores -~3us, merge reads -~3us
//    (2.2 MB/XCD slice now L2-resident), wg prologues halve (1024 -> 512).
//  - Load balance at 2-resident/CU with no backfill: stride-8 pair->XCD
//    map (pair = xcd + 8*(r&15)) equalizes per-XCD work (old contiguous
//    map would give center XCDs ~33% more); all 4 ck-wgs of a pair stay
//    on one XCD sharing its band in L2.

typedef _Float16 f16;
typedef __attribute__((ext_vector_type(8))) _Float16 f16x8;
typedef __attribute__((ext_vector_type(4))) _Float16 f16x4;
typedef __attribute__((ext_vector_type(4))) float f32x4;
typedef __attribute__((ext_vector_type(8))) short short8;
typedef __attribute__((ext_vector_type(4))) unsigned short u16x4;
typedef __attribute__((ext_vector_type(8))) unsigned short u16x8;

#define MFMA16(a, b, c) __builtin_amdgcn_mfma_f32_16x16x32_f16((a), (b), (c), 0, 0, 0)
#define MFMABF(a, b, c) __builtin_amdgcn_mfma_f32_16x16x32_bf16((a), (b), (c), 0, 0, 0)

#define BATCH 4
#define SEQ   4096
#define DIM   128
#define NB    64
#define WBAND 32
#define LOG2E 1.44269504088896f
#define TSTR  72

#define TILE  16384   // one K or V tile in fragment order: 16 frags x 64 lanes x 16B
#define CHUNKS 4
#define PART_STRIDE 16896  // 16KB o (f16 [2 qh][8 slot][64 lane][16B]) + 512B (m,l)

// LDS slots: KA@0, KB@16384, VA@32768, VB@49152
#define KA_OFF 0
#define KB_OFF 16384
#define VA_OFF 32768
#define VB_OFF 49152

#define WAIT0 asm volatile("s_waitcnt vmcnt(0)" ::: "memory")

__device__ __forceinline__ void gl16(const char* g, char* l) {
  __builtin_amdgcn_global_load_lds(
      (const __attribute__((address_space(1))) void*)g,
      (__attribute__((address_space(3))) void*)l, 16, 0, 0);
}

__device__ __forceinline__ unsigned int pk_bf16(float a, float b) {
  unsigned int r;
  asm("v_cvt_pk_bf16_f32 %0, %1, %2" : "=v"(r) : "v"(a), "v"(b));
  return r;  // lo16 = bf16(a), hi16 = bf16(b)
}

__device__ __forceinline__ unsigned short f2bf(float x) {  // RTN f32->bf16
  unsigned int u = __float_as_uint(x);
  u += 0x7FFFu + ((u >> 16) & 1u);
  return (unsigned short)(u >> 16);
}

// ---------------------------------------------------------------------------
// Packs K (f16) and V (bf16) into MFMA fragment order, plus V column sums BS.
// KF frag(ks,jt), lane l: K[s0 + jt*16 + (l&15)][ks*32 + (l>>4)*8 + e]
// VF frag(ks2,nt), lane l: V[s0 + ks2*32 + (e>>2)*16 + ((l>>4)&3)*4 + (e&3)]
//                           [nt*16 + (l&15)]   (pi-permuted contraction rows)
__global__ __launch_bounds__(256) void convert_kernel(
    const float* __restrict__ K, const float* __restrict__ V,
    f16* __restrict__ KF, unsigned short* __restrict__ VF,
    float* __restrict__ BS) {
  __shared__ unsigned short T[128 * TSTR];  // bf16 bits
  const int blk = blockIdx.x;
  const int b = blk >> 6, jb = blk & 63;
  const int s0 = jb * 64;
  const int t = threadIdx.x;

  // V -> T (d-major transpose, bf16)
#pragma unroll
  for (int i = 0; i < 8; ++i) {
    int idx = t + i * 256;
    int row = idx >> 5;
    int c4 = (idx & 31) * 4;
    float4 v = *(const float4*)(V + (size_t)(b * SEQ + s0 + row) * DIM + c4);
    T[(c4 + 0) * TSTR + row] = f2bf(v.x);
    T[(c4 + 1) * TSTR + row] = f2bf(v.y);
    T[(c4 + 2) * TSTR + row] = f2bf(v.z);
    T[(c4 + 3) * TSTR + row] = f2bf(v.w);
  }

  // KF fragments (f16, no LDS needed)
  char* kt = (char*)KF + (size_t)blk * TILE;
#pragma unroll
  for (int i = 0; i < 4; ++i) {
    int idx = t + i * 256;           // frag*64 + lane
    int frag = idx >> 6, lane = idx & 63;
    int ks = frag >> 2, jt = frag & 3;
    int row = jt * 16 + (lane & 15);
    int d0 = ks * 32 + (lane >> 4) * 8;
    const float* src = K + ((size_t)(b * SEQ + s0 + row)) * DIM + d0;
    float4 a = *(const float4*)src;
    float4 d = *(const float4*)(src + 4);
    f16x8 h = {(f16)a.x, (f16)a.y, (f16)a.z, (f16)a.w,
               (f16)d.x, (f16)d.y, (f16)d.z, (f16)d.w};
    *(f16x8*)(kt + idx * 16) = h;
  }
  __syncthreads();

  // VF fragments (bf16) with pi row-permutation, gathered from T
  char* vt = (char*)VF + (size_t)blk * TILE;
#pragma unroll
  for (int i = 0; i < 4; ++i) {
    int idx = t + i * 256;
    int frag = idx >> 6, lane = idx & 63;
    int ks2 = frag >> 3, nt = frag & 7;
    int d = nt * 16 + (lane & 15);
    int k0 = ks2 * 32 + ((lane >> 4) & 3) * 4;
    u16x4 x = *(const u16x4*)(T + d * TSTR + k0);
    u16x4 y = *(const u16x4*)(T + d * TSTR + k0 + 16);
    u16x8 h = {x[0], x[1], x[2], x[3], y[0], y[1], y[2], y[3]};
    *(u16x8*)(vt + idx * 16) = h;
  }

  if (t < 128) {
    float s = 0.f;
    for (int k = 0; k < 64; ++k)
      s += __uint_as_float(((unsigned int)T[t * TSTR + k]) << 16);
    BS[(b * NB + jb) * DIM + t] = s;
  }
}

// ---------------------------------------------------------------------------
// Pair-wg attention; 2 tiles per barrier period, single-buffered 64KB group.
__global__ __launch_bounds__(256, 2) void attn_kernel(
    const float* __restrict__ Q, const f16* __restrict__ KF,
    const unsigned short* __restrict__ VF, char* __restrict__ PART) {
  __shared__ __align__(16) char smem[65536];

  const int id = blockIdx.x;
  // balanced XCD map: XCD x gets pairs {x, x+8, ..., x+120} (equal work),
  // and all 4 ck-wgs of a pair land on the same XCD (shared band in L2).
  const int x = id & 7;
  const int r = id >> 3;            // 0..63
  const int pair = x + 8 * (r & 15);  // 0..127
  const int ck = r >> 4;            // 0..3
  const int b = pair >> 5, p = pair & 31;

  const int t = threadIdx.x;
  const int w = t >> 6, l = t & 63, lg = l >> 4, ll = l & 15;
  const int half = w >> 1, qh = w & 1;   // wave -> (block-in-pair, q-half)
  const int myib = p * 2 + half;

  const int jloU = max(0, p * 2 - WBAND);
  const int jhiU = min(NB, p * 2 + 1 + WBAND);
  const int lenU = jhiU - jloU;            // 33..64
  const int base = lenU >> 2, rem = lenU & 3;
  const int j0 = jloU + ck * base + min(ck, rem);
  const int nloc = base + (ck < rem ? 1 : 0);   // 8..16, never empty
  const int mylo = max(0, myib - WBAND);
  const int myhi = min(NB, myib + WBAND);

  // Q fragments (pre-scaled by log2 e), loaded f32 direct from global.
  f16x8 qf[2][4];
#pragma unroll
  for (int s = 0; s < 2; ++s) {
    const float* qrow =
        Q + ((size_t)(b * SEQ + myib * 64 + qh * 32 + s * 16 + ll)) * DIM;
#pragma unroll
    for (int ks = 0; ks < 4; ++ks) {
      int d0 = ks * 32 + lg * 8;
      float4 a = *(const float4*)(qrow + d0);
      float4 cc = *(const float4*)(qrow + d0 + 4);
      float vv[8] = {a.x, a.y, a.z, a.w, cc.x, cc.y, cc.z, cc.w};
#pragma unroll
      for (int e = 0; e < 8; ++e) qf[s][ks][e] = (f16)(vv[e] * LOG2E);
    }
  }

  float ell[2] = {0.f, 0.f};  // per-lane partial row sums of 2^S (raw scale)
  f32x4 o[2][8];
#pragma unroll
  for (int s = 0; s < 2; ++s)
#pragma unroll
    for (int nt = 0; nt < 8; ++nt) o[s][nt] = (f32x4){0.f, 0.f, 0.f, 0.f};

  // stage group g: tiles j0+2g (A slots) and j0+2g+1 (B slots, if valid)
  auto stage_group = [&](int g) {
    const int jA = j0 + 2 * g;
    {
      const char* kg = (const char*)KF + ((size_t)(b * NB + jA)) * TILE + t * 16;
      const char* vg = (const char*)VF + ((size_t)(b * NB + jA)) * TILE + t * 16;
#pragma unroll
      for (int i = 0; i < 4; ++i) gl16(kg + i * 4096, smem + KA_OFF + t * 16 + i * 4096);
#pragma unroll
      for (int i = 0; i < 4; ++i) gl16(vg + i * 4096, smem + VA_OFF + t * 16 + i * 4096);
    }
    if (2 * g + 1 < nloc) {
      const int jB = jA + 1;
      const char* kg = (const char*)KF + ((size_t)(b * NB + jB)) * TILE + t * 16;
      const char* vg = (const char*)VF + ((size_t)(b * NB + jB)) * TILE + t * 16;
#pragma unroll
      for (int i = 0; i < 4; ++i) gl16(kg + i * 4096, smem + KB_OFF + t * 16 + i * 4096);
#pragma unroll
      for (int i = 0; i < 4; ++i) gl16(vg + i * 4096, smem + VB_OFF + t * 16 + i * 4096);
    }
  };

  // one tile visit: QK^T + raw-exp2 P (bf16) + PV  -- no softmax state
  auto compute = [&](int j, const char* kb, const char* vb) {
    if (j < mylo || j >= myhi) return;  // wave-uniform

    // ---- QK^T (swapped, f16): sacc[s][jt][r] = S[q][key = jt*16+lg*4+r]
    f32x4 sacc[2][4];
#pragma unroll
    for (int s = 0; s < 2; ++s)
#pragma unroll
      for (int jt = 0; jt < 4; ++jt) sacc[s][jt] = (f32x4){0.f, 0.f, 0.f, 0.f};

    __builtin_amdgcn_s_setprio(1);
#pragma unroll
    for (int ks = 0; ks < 4; ++ks) {
#pragma unroll
      for (int jt = 0; jt < 4; ++jt) {
        f16x8 kf = *(const f16x8*)(kb + (ks * 4 + jt) * 1024 + l * 16);
        sacc[0][jt] = MFMA16(kf, qf[0][ks], sacc[0][jt]);
        sacc[1][jt] = MFMA16(kf, qf[1][ks], sacc[1][jt]);
      }
    }
    __builtin_amdgcn_s_setprio(0);

    // ---- P = 2^S raw, packed to bf16 (lane-local; pi-V ordering)
    short8 pa[2][2];
#pragma unroll
    for (int s = 0; s < 2; ++s) {
      float rsum = 0.f;
#pragma unroll
      for (int ks2 = 0; ks2 < 2; ++ks2) {
        float pe[8];
#pragma unroll
        for (int u = 0; u < 2; ++u)
#pragma unroll
          for (int r4 = 0; r4 < 4; ++r4) {
            float pv = __builtin_amdgcn_exp2f(sacc[s][ks2 * 2 + u][r4]);
            rsum += pv;
            pe[u * 4 + r4] = pv;
          }
        union { unsigned int w2[4]; short8 v; } pk;
#pragma unroll
        for (int h2 = 0; h2 < 4; ++h2)
          pk.w2[h2] = pk_bf16(pe[h2 * 2], pe[h2 * 2 + 1]);
        pa[s][ks2] = pk.v;
      }
      ell[s] += rsum;
    }

    // ---- PV (bf16): B = pi-permuted V fragments from LDS
    __builtin_amdgcn_s_setprio(1);
#pragma unroll
    for (int ks2 = 0; ks2 < 2; ++ks2) {
#pragma unroll
      for (int nt = 0; nt < 8; ++nt) {
        short8 vbf = *(const short8*)(vb + (ks2 * 8 + nt) * 1024 + l * 16);
        o[0][nt] = MFMABF(pa[0][ks2], vbf, o[0][nt]);
        o[1][nt] = MFMABF(pa[1][ks2], vbf, o[1][nt]);
      }
    }
    __builtin_amdgcn_s_setprio(0);
  };

  const int ng = (nloc + 1) >> 1;
  stage_group(0);
  for (int g = 0; g < ng; ++g) {
    WAIT0;             // own gl16s of group g complete
    __syncthreads();   // all waves' LDS writes visible; buffer handoff

    compute(j0 + 2 * g, smem + KA_OFF, smem + VA_OFF);
    if (2 * g + 1 < nloc)
      compute(j0 + 2 * g + 1, smem + KB_OFF, smem + VB_OFF);

    __syncthreads();   // everyone done reading group g
    if (g + 1 < ng) stage_group(g + 1);
  }

  // finalize per-row sums across lg lanes (once per chunk)
#pragma unroll
  for (int s = 0; s < 2; ++s) {
    ell[s] += __shfl_xor(ell[s], 16);
    ell[s] += __shfl_xor(ell[s], 32);
  }

  // normalize o by per-row 1/ell so the f16 PART store stays in range;
  // broadcast rinv from q-row lanes (ll) to o-row layout (lg*4+r)
  float sb[2][4];
#pragma unroll
  for (int s = 0; s < 2; ++s) {
    float rinv = 1.f / ell[s];
#pragma unroll
    for (int r4 = 0; r4 < 4; ++r4) sb[s][r4] = __shfl(rinv, lg * 4 + r4);
  }

  // partial store, coalesced 16B/lane: [qh][slot=s*4+g][lane][16B]
  char* pb = PART + ((size_t)((pair * CHUNKS + ck) * 2 + half)) * PART_STRIDE;
#pragma unroll
  for (int s = 0; s < 2; ++s)
#pragma unroll
    for (int g = 0; g < 4; ++g) {
      f16x8 hh;
#pragma unroll
      for (int r4 = 0; r4 < 4; ++r4) {
        hh[r4] = (f16)(o[s][2 * g][r4] * sb[s][r4]);
        hh[4 + r4] = (f16)(o[s][2 * g + 1][r4] * sb[s][r4]);
      }
      *(f16x8*)(pb + qh * 8192 + ((s * 4 + g) * 64 + l) * 16) = hh;
    }
  if (lg == 0) {
#pragma unroll
    for (int s = 0; s < 2; ++s)
      *(float2*)(pb + 16384 + (qh * 32 + s * 16 + ll) * 8) =
          make_float2(0.f, ell[s]);
  }
}

// ---------------------------------------------------------------------------
// Merge: weighted sum of chunk partials (w_k = ell_k, raw-2^S scale) +
// out-of-band term with weight 1 per entry. No exp2 / flash math needed.
__global__ __launch_bounds__(256) void merge_kernel(
    const char* __restrict__ PART, const float* __restrict__ BS,
    float* __restrict__ Out) {
  __shared__ float VoutS[DIM];
  __shared__ float mlS[CHUNKS][64][2];

  const int id = blockIdx.x;
  const int lin = (id & 7) * 32 + (id >> 3);  // 256 wgs
  const int pair = lin >> 1, half = lin & 1;
  const int b = pair >> 5;
  const int ib = (pair & 31) * 2 + half;
  const int t = threadIdx.x;
  const int l = t & 63, lg = (t >> 4) & 3, ll = t & 15;
  const int sub = (t >> 6) & 1, qh = t >> 7;

  const int jlo = max(0, ib - WBAND);
  const int jhi = min(NB, ib + WBAND);
  const float cnt_out = (float)(SEQ - (jhi - jlo) * 64);

  if (t < DIM) {
    float s = 0.f;
    for (int j = 0; j < jlo; ++j) s += BS[(b * NB + j) * DIM + t];
    for (int j = jhi; j < NB; ++j) s += BS[(b * NB + j) * DIM + t];
    VoutS[t] = s;
  }

  const size_t pb0 = ((size_t)(pair * CHUNKS * 2 + half)) * PART_STRIDE;
  for (int i = t; i < CHUNKS * 64; i += 256) {
    int k = i >> 6, row = i & 63;
    *(float2*)&mlS[k][row][0] = *(const float2*)(
        PART + pb0 + (size_t)k * 2 * PART_STRIDE + 16384 + row * 8);
  }
  __syncthreads();

  float aw[4][CHUNKS], inv[4];
#pragma unroll
  for (int r = 0; r < 4; ++r) {
    int row = qh * 32 + sub * 16 + lg * 4 + r;
    float den = cnt_out;
#pragma unroll
    for (int k = 0; k < CHUNKS; ++k) {
      aw[r][k] = mlS[k][row][1];
      den += aw[r][k];
    }
    inv[r] = 1.f / den;
  }

  float acc[8][4];
#pragma unroll
  for (int nt = 0; nt < 8; ++nt)
#pragma unroll
    for (int r = 0; r < 4; ++r) acc[nt][r] = 0.f;

  for (int k = 0; k < CHUNKS; ++k) {
    const char* oc = PART + pb0 + (size_t)k * 2 * PART_STRIDE + qh * 8192;
#pragma unroll
    for (int g = 0; g < 4; ++g) {
      f16x8 h = *(const f16x8*)(oc + ((sub * 4 + g) * 64 + l) * 16);
#pragma unroll
      for (int r = 0; r < 4; ++r) {
        acc[2 * g][r] += aw[r][k] * (float)h[r];
        acc[2 * g + 1][r] += aw[r][k] * (float)h[4 + r];
      }
    }
  }

  const int q0 = ib * 64;
#pragma unroll
  for (int nt = 0; nt < 8; ++nt) {
    int col = nt * 16 + ll;
    float vout = VoutS[col];
#pragma unroll
    for (int r = 0; r < 4; ++r) {
      int row = qh * 32 + sub * 16 + lg * 4 + r;
      Out[((size_t)(b * SEQ + q0 + row)) * DIM + col] =
          (acc[nt][r] + vout) * inv[r];
    }
  }
}

// ---------------------------------------------------------------------------
extern "C" void kernel_launch(void* const* d_in, const int* in_sizes, int n_in,
                              void* d_out, int out_size, void* d_ws, size_t ws_size,
                              hipStream_t stream) {
  const float* Q = (const float*)d_in[0];
  const float* K = (const float*)d_in[1];
  const float* V = (const float*)d_in[2];
  float* Out = (float*)d_out;

  char* ws = (char*)d_ws;
  f16* KF = (f16*)ws;                                   // 4 MB
  unsigned short* VF = (unsigned short*)(ws + (size_t)BATCH * NB * TILE);  // 4 MB
  float* BS = (float*)(ws + 2 * (size_t)BATCH * NB * TILE);  // 128 KB
  char* PART = ws + 2 * (size_t)BATCH * NB * TILE + (size_t)BATCH * NB * DIM * 4;

  convert_kernel<<<dim3(BATCH * NB), 256, 0, stream>>>(K, V, KF, VF, BS);
  attn_kernel<<<dim3(BATCH * NB / 2 * CHUNKS), 256, 0, stream>>>(Q, KF, VF, PART);
  merge_kernel<<<dim3(BATCH * NB), 256, 0, stream>>>(PART, BS, Out);
}

// Round 16
// 58.600 us; speedup vs baseline: 1.0623x; 1.0623x over previous
//
#include <hip/hip_runtime.h>

// Banded-block sparse attention, B=4, S=4096, D=128, block=64, w=32.
// Masked scores are 0 (not -inf) -> closed-form out-of-band correction.
//
// R16 = R12 convert+attn VERBATIM (best verified: raw-2^S bf16-P softmax,
// V-in-LDS, 2 tiles/barrier period, pair-wg, CHUNKS=8, contiguous XCD map)
// + merge split by d-half: grid 256 -> 512 (2 wg/CU), each wg reads half
// the o-slots per chunk (64 KB vs 132 KB) -> latency better hidden, same
// total bytes. Merge math unchanged (weighted sum, w_k = ell_k).

typedef _Float16 f16;
typedef __attribute__((ext_vector_type(8))) _Float16 f16x8;
typedef __attribute__((ext_vector_type(4))) _Float16 f16x4;
typedef __attribute__((ext_vector_type(4))) float f32x4;
typedef __attribute__((ext_vector_type(8))) short short8;
typedef __attribute__((ext_vector_type(4))) unsigned short u16x4;
typedef __attribute__((ext_vector_type(8))) unsigned short u16x8;

#define MFMA16(a, b, c) __builtin_amdgcn_mfma_f32_16x16x32_f16((a), (b), (c), 0, 0, 0)
#define MFMABF(a, b, c) __builtin_amdgcn_mfma_f32_16x16x32_bf16((a), (b), (c), 0, 0, 0)

#define BATCH 4
#define SEQ   4096
#define DIM   128
#define NB    64
#define WBAND 32
#define LOG2E 1.44269504088896f
#define TSTR  72

#define TILE  16384   // one K or V tile in fragment order: 16 frags x 64 lanes x 16B
#define CHUNKS 8
#define PART_STRIDE 16896  // 16KB o (f16 [2 qh][8 slot][64 lane][16B]) + 512B (m,l)

// LDS slots: KA@0, KB@16384, VA@32768, VB@49152
#define KA_OFF 0
#define KB_OFF 16384
#define VA_OFF 32768
#define VB_OFF 49152

#define WAIT0 asm volatile("s_waitcnt vmcnt(0)" ::: "memory")

__device__ __forceinline__ void gl16(const char* g, char* l) {
  __builtin_amdgcn_global_load_lds(
      (const __attribute__((address_space(1))) void*)g,
      (__attribute__((address_space(3))) void*)l, 16, 0, 0);
}

__device__ __forceinline__ unsigned int pk_bf16(float a, float b) {
  unsigned int r;
  asm("v_cvt_pk_bf16_f32 %0, %1, %2" : "=v"(r) : "v"(a), "v"(b));
  return r;  // lo16 = bf16(a), hi16 = bf16(b)
}

__device__ __forceinline__ unsigned short f2bf(float x) {  // RTN f32->bf16
  unsigned int u = __float_as_uint(x);
  u += 0x7FFFu + ((u >> 16) & 1u);
  return (unsigned short)(u >> 16);
}

// ---------------------------------------------------------------------------
// Packs K (f16) and V (bf16) into MFMA fragment order, plus V column sums BS.
// KF frag(ks,jt), lane l: K[s0 + jt*16 + (l&15)][ks*32 + (l>>4)*8 + e]
// VF frag(ks2,nt), lane l: V[s0 + ks2*32 + (e>>2)*16 + ((l>>4)&3)*4 + (e&3)]
//                           [nt*16 + (l&15)]   (pi-permuted contraction rows)
__global__ __launch_bounds__(256) void convert_kernel(
    const float* __restrict__ K, const float* __restrict__ V,
    f16* __restrict__ KF, unsigned short* __restrict__ VF,
    float* __restrict__ BS) {
  __shared__ unsigned short T[128 * TSTR];  // bf16 bits
  const int blk = blockIdx.x;
  const int b = blk >> 6, jb = blk & 63;
  const int s0 = jb * 64;
  const int t = threadIdx.x;

  // V -> T (d-major transpose, bf16)
#pragma unroll
  for (int i = 0; i < 8; ++i) {
    int idx = t + i * 256;
    int row = idx >> 5;
    int c4 = (idx & 31) * 4;
    float4 v = *(const float4*)(V + (size_t)(b * SEQ + s0 + row) * DIM + c4);
    T[(c4 + 0) * TSTR + row] = f2bf(v.x);
    T[(c4 + 1) * TSTR + row] = f2bf(v.y);
    T[(c4 + 2) * TSTR + row] = f2bf(v.z);
    T[(c4 + 3) * TSTR + row] = f2bf(v.w);
  }

  // KF fragments (f16, no LDS needed)
  char* kt = (char*)KF + (size_t)blk * TILE;
#pragma unroll
  for (int i = 0; i < 4; ++i) {
    int idx = t + i * 256;           // frag*64 + lane
    int frag = idx >> 6, lane = idx & 63;
    int ks = frag >> 2, jt = frag & 3;
    int row = jt * 16 + (lane & 15);
    int d0 = ks * 32 + (lane >> 4) * 8;
    const float* src = K + ((size_t)(b * SEQ + s0 + row)) * DIM + d0;
    float4 a = *(const float4*)src;
    float4 d = *(const float4*)(src + 4);
    f16x8 h = {(f16)a.x, (f16)a.y, (f16)a.z, (f16)a.w,
               (f16)d.x, (f16)d.y, (f16)d.z, (f16)d.w};
    *(f16x8*)(kt + idx * 16) = h;
  }
  __syncthreads();

  // VF fragments (bf16) with pi row-permutation, gathered from T
  char* vt = (char*)VF + (size_t)blk * TILE;
#pragma unroll
  for (int i = 0; i < 4; ++i) {
    int idx = t + i * 256;
    int frag = idx >> 6, lane = idx & 63;
    int ks2 = frag >> 3, nt = frag & 7;
    int d = nt * 16 + (lane & 15);
    int k0 = ks2 * 32 + ((lane >> 4) & 3) * 4;
    u16x4 x = *(const u16x4*)(T + d * TSTR + k0);
    u16x4 y = *(const u16x4*)(T + d * TSTR + k0 + 16);
    u16x8 h = {x[0], x[1], x[2], x[3], y[0], y[1], y[2], y[3]};
    *(u16x8*)(vt + idx * 16) = h;
  }

  if (t < 128) {
    float s = 0.f;
    for (int k = 0; k < 64; ++k)
      s += __uint_as_float(((unsigned int)T[t * TSTR + k]) << 16);
    BS[(b * NB + jb) * DIM + t] = s;
  }
}

// ---------------------------------------------------------------------------
// Pair-wg attention; 2 tiles per barrier period, single-buffered 64KB group.
// (R12 verbatim)
__global__ __launch_bounds__(256, 2) void attn_kernel(
    const float* __restrict__ Q, const f16* __restrict__ KF,
    const unsigned short* __restrict__ VF, char* __restrict__ PART) {
  __shared__ __align__(16) char smem[65536];

  const int id = blockIdx.x;
  const int lin = (id & 7) * 128 + (id >> 3);  // XCD-contiguous pair bands
  const int ck = lin & 7;
  const int pair = lin >> 3;   // 0..127
  const int b = pair >> 5, p = pair & 31;

  const int t = threadIdx.x;
  const int w = t >> 6, l = t & 63, lg = l >> 4, ll = l & 15;
  const int half = w >> 1, qh = w & 1;   // wave -> (block-in-pair, q-half)
  const int myib = p * 2 + half;

  const int jloU = max(0, p * 2 - WBAND);
  const int jhiU = min(NB, p * 2 + 1 + WBAND);
  const int lenU = jhiU - jloU;            // 33..64
  const int base = lenU >> 3, rem = lenU & 7;
  const int j0 = jloU + ck * base + min(ck, rem);
  const int nloc = base + (ck < rem ? 1 : 0);   // 4..8, never empty
  const int mylo = max(0, myib - WBAND);
  const int myhi = min(NB, myib + WBAND);

  // Q fragments (pre-scaled by log2 e), loaded f32 direct from global.
  f16x8 qf[2][4];
#pragma unroll
  for (int s = 0; s < 2; ++s) {
    const float* qrow =
        Q + ((size_t)(b * SEQ + myib * 64 + qh * 32 + s * 16 + ll)) * DIM;
#pragma unroll
    for (int ks = 0; ks < 4; ++ks) {
      int d0 = ks * 32 + lg * 8;
      float4 a = *(const float4*)(qrow + d0);
      float4 cc = *(const float4*)(qrow + d0 + 4);
      float vv[8] = {a.x, a.y, a.z, a.w, cc.x, cc.y, cc.z, cc.w};
#pragma unroll
      for (int e = 0; e < 8; ++e) qf[s][ks][e] = (f16)(vv[e] * LOG2E);
    }
  }

  float ell[2] = {0.f, 0.f};  // per-lane partial row sums of 2^S (raw scale)
  f32x4 o[2][8];
#pragma unroll
  for (int s = 0; s < 2; ++s)
#pragma unroll
    for (int nt = 0; nt < 8; ++nt) o[s][nt] = (f32x4){0.f, 0.f, 0.f, 0.f};

  // stage group g: tiles j0+2g (A slots) and j0+2g+1 (B slots, if valid)
  auto stage_group = [&](int g) {
    const int jA = j0 + 2 * g;
    {
      const char* kg = (const char*)KF + ((size_t)(b * NB + jA)) * TILE + t * 16;
      const char* vg = (const char*)VF + ((size_t)(b * NB + jA)) * TILE + t * 16;
#pragma unroll
      for (int i = 0; i < 4; ++i) gl16(kg + i * 4096, smem + KA_OFF + t * 16 + i * 4096);
#pragma unroll
      for (int i = 0; i < 4; ++i) gl16(vg + i * 4096, smem + VA_OFF + t * 16 + i * 4096);
    }
    if (2 * g + 1 < nloc) {
      const int jB = jA + 1;
      const char* kg = (const char*)KF + ((size_t)(b * NB + jB)) * TILE + t * 16;
      const char* vg = (const char*)VF + ((size_t)(b * NB + jB)) * TILE + t * 16;
#pragma unroll
      for (int i = 0; i < 4; ++i) gl16(kg + i * 4096, smem + KB_OFF + t * 16 + i * 4096);
#pragma unroll
      for (int i = 0; i < 4; ++i) gl16(vg + i * 4096, smem + VB_OFF + t * 16 + i * 4096);
    }
  };

  // one tile visit: QK^T + raw-exp2 P (bf16) + PV  -- no softmax state
  auto compute = [&](int j, const char* kb, const char* vb) {
    if (j < mylo || j >= myhi) return;  // wave-uniform

    // ---- QK^T (swapped, f16): sacc[s][jt][r] = S[q][key = jt*16+lg*4+r]
    f32x4 sacc[2][4];
#pragma unroll
    for (int s = 0; s < 2; ++s)
#pragma unroll
      for (int jt = 0; jt < 4; ++jt) sacc[s][jt] = (f32x4){0.f, 0.f, 0.f, 0.f};

    __builtin_amdgcn_s_setprio(1);
#pragma unroll
    for (int ks = 0; ks < 4; ++ks) {
#pragma unroll
      for (int jt = 0; jt < 4; ++jt) {
        f16x8 kf = *(const f16x8*)(kb + (ks * 4 + jt) * 1024 + l * 16);
        sacc[0][jt] = MFMA16(kf, qf[0][ks], sacc[0][jt]);
        sacc[1][jt] = MFMA16(kf, qf[1][ks], sacc[1][jt]);
      }
    }
    __builtin_amdgcn_s_setprio(0);

    // ---- P = 2^S raw, packed to bf16 (lane-local; pi-V ordering)
    short8 pa[2][2];
#pragma unroll
    for (int s = 0; s < 2; ++s) {
      float rsum = 0.f;
#pragma unroll
      for (int ks2 = 0; ks2 < 2; ++ks2) {
        float pe[8];
#pragma unroll
        for (int u = 0; u < 2; ++u)
#pragma unroll
          for (int r4 = 0; r4 < 4; ++r4) {
            float pv = __builtin_amdgcn_exp2f(sacc[s][ks2 * 2 + u][r4]);
            rsum += pv;
            pe[u * 4 + r4] = pv;
          }
        union { unsigned int w2[4]; short8 v; } pk;
#pragma unroll
        for (int h2 = 0; h2 < 4; ++h2)
          pk.w2[h2] = pk_bf16(pe[h2 * 2], pe[h2 * 2 + 1]);
        pa[s][ks2] = pk.v;
      }
      ell[s] += rsum;
    }

    // ---- PV (bf16): B = pi-permuted V fragments from LDS
    __builtin_amdgcn_s_setprio(1);
#pragma unroll
    for (int ks2 = 0; ks2 < 2; ++ks2) {
#pragma unroll
      for (int nt = 0; nt < 8; ++nt) {
        short8 vbf = *(const short8*)(vb + (ks2 * 8 + nt) * 1024 + l * 16);
        o[0][nt] = MFMABF(pa[0][ks2], vbf, o[0][nt]);
        o[1][nt] = MFMABF(pa[1][ks2], vbf, o[1][nt]);
      }
    }
    __builtin_amdgcn_s_setprio(0);
  };

  const int ng = (nloc + 1) >> 1;
  stage_group(0);
  for (int g = 0; g < ng; ++g) {
    WAIT0;             // own gl16s of group g complete
    __syncthreads();   // all waves' LDS writes visible; buffer handoff

    compute(j0 + 2 * g, smem + KA_OFF, smem + VA_OFF);
    if (2 * g + 1 < nloc)
      compute(j0 + 2 * g + 1, smem + KB_OFF, smem + VB_OFF);

    __syncthreads();   // everyone done reading group g
    if (g + 1 < ng) stage_group(g + 1);
  }

  // finalize per-row sums across lg lanes (once per chunk)
#pragma unroll
  for (int s = 0; s < 2; ++s) {
    ell[s] += __shfl_xor(ell[s], 16);
    ell[s] += __shfl_xor(ell[s], 32);
  }

  // normalize o by per-row 1/ell so the f16 PART store stays in range;
  // broadcast rinv from q-row lanes (ll) to o-row layout (lg*4+r)
  float sb[2][4];
#pragma unroll
  for (int s = 0; s < 2; ++s) {
    float rinv = 1.f / ell[s];
#pragma unroll
    for (int r4 = 0; r4 < 4; ++r4) sb[s][r4] = __shfl(rinv, lg * 4 + r4);
  }

  // partial store, coalesced 16B/lane: [qh][slot=s*4+g][lane][16B]
  char* pb = PART + ((size_t)((pair * CHUNKS + ck) * 2 + half)) * PART_STRIDE;
#pragma unroll
  for (int s = 0; s < 2; ++s)
#pragma unroll
    for (int g = 0; g < 4; ++g) {
      f16x8 hh;
#pragma unroll
      for (int r4 = 0; r4 < 4; ++r4) {
        hh[r4] = (f16)(o[s][2 * g][r4] * sb[s][r4]);
        hh[4 + r4] = (f16)(o[s][2 * g + 1][r4] * sb[s][r4]);
      }
      *(f16x8*)(pb + qh * 8192 + ((s * 4 + g) * 64 + l) * 16) = hh;
    }
  if (lg == 0) {
#pragma unroll
    for (int s = 0; s < 2; ++s)
      *(float2*)(pb + 16384 + (qh * 32 + s * 16 + ll) * 8) =
          make_float2(0.f, ell[s]);
  }
}

// ---------------------------------------------------------------------------
// Merge: weighted sum of chunk partials (w_k = ell_k, raw-2^S scale) +
// out-of-band term with weight 1 per entry. Split by d-half: grid 512,
// wg = (pair, half, dh); each wg reads slots {s*4 + dh*2 + g} only.
__global__ __launch_bounds__(256) void merge_kernel(
    const char* __restrict__ PART, const float* __restrict__ BS,
    float* __restrict__ Out) {
  __shared__ float VoutS[DIM];
  __shared__ float mlS[CHUNKS][64][2];

  const int id = blockIdx.x;
  const int lin = (id & 7) * 64 + (id >> 3);  // XCD-contiguous pairs (match attn)
  const int pair = lin >> 2;
  const int half = (lin >> 1) & 1;
  const int dh = lin & 1;
  const int b = pair >> 5;
  const int ib = (pair & 31) * 2 + half;
  const int t = threadIdx.x;
  const int l = t & 63, lg = (t >> 4) & 3, ll = t & 15;
  const int sub = (t >> 6) & 1, qh = t >> 7;

  const int jlo = max(0, ib - WBAND);
  const int jhi = min(NB, ib + WBAND);
  const float cnt_out = (float)(SEQ - (jhi - jlo) * 64);

  if (t < DIM) {
    float s = 0.f;
    for (int j = 0; j < jlo; ++j) s += BS[(b * NB + j) * DIM + t];
    for (int j = jhi; j < NB; ++j) s += BS[(b * NB + j) * DIM + t];
    VoutS[t] = s;
  }

  const size_t pb0 = ((size_t)(pair * CHUNKS * 2 + half)) * PART_STRIDE;
  for (int i = t; i < CHUNKS * 64; i += 256) {
    int k = i >> 6, row = i & 63;
    *(float2*)&mlS[k][row][0] = *(const float2*)(
        PART + pb0 + (size_t)k * 2 * PART_STRIDE + 16384 + row * 8);
  }
  __syncthreads();

  float aw[4][CHUNKS], inv[4];
#pragma unroll
  for (int r = 0; r < 4; ++r) {
    int row = qh * 32 + sub * 16 + lg * 4 + r;
    float den = cnt_out;
#pragma unroll
    for (int k = 0; k < CHUNKS; ++k) {
      aw[r][k] = mlS[k][row][1];
      den += aw[r][k];
    }
    inv[r] = 1.f / den;
  }

  float acc[4][4];
#pragma unroll
  for (int n2 = 0; n2 < 4; ++n2)
#pragma unroll
    for (int r = 0; r < 4; ++r) acc[n2][r] = 0.f;

  for (int k = 0; k < CHUNKS; ++k) {
    const char* oc = PART + pb0 + (size_t)k * 2 * PART_STRIDE + qh * 8192;
#pragma unroll
    for (int g = 0; g < 2; ++g) {
      int slot = sub * 4 + dh * 2 + g;
      f16x8 h = *(const f16x8*)(oc + (slot * 64 + l) * 16);
#pragma unroll
      for (int r = 0; r < 4; ++r) {
        acc[2 * g][r] += aw[r][k] * (float)h[r];
        acc[2 * g + 1][r] += aw[r][k] * (float)h[4 + r];
      }
    }
  }

  const int q0 = ib * 64;
#pragma unroll
  for (int n2 = 0; n2 < 4; ++n2) {
    int nt = dh * 4 + n2;            // stored slot g covers nt = 2g, 2g+1
    int col = nt * 16 + ll;
    float vout = VoutS[col];
#pragma unroll
    for (int r = 0; r < 4; ++r) {
      int row = qh * 32 + sub * 16 + lg * 4 + r;
      Out[((size_t)(b * SEQ + q0 + row)) * DIM + col] =
          (acc[n2][r] + vout) * inv[r];
    }
  }
}

// ---------------------------------------------------------------------------
extern "C" void kernel_launch(void* const* d_in, const int* in_sizes, int n_in,
                              void* d_out, int out_size, void* d_ws, size_t ws_size,
                              hipStream_t stream) {
  const float* Q = (const float*)d_in[0];
  const float* K = (const float*)d_in[1];
  const float* V = (const float*)d_in[2];
  float* Out = (float*)d_out;

  char* ws = (char*)d_ws;
  f16* KF = (f16*)ws;                                   // 4 MB
  unsigned short* VF = (unsigned short*)(ws + (size_t)BATCH * NB * TILE);  // 4 MB
  float* BS = (float*)(ws + 2 * (size_t)BATCH * NB * TILE);  // 128 KB
  char* PART = ws + 2 * (size_t)BATCH * NB * TILE + (size_t)BATCH * NB * DIM * 4;

  convert_kernel<<<dim3(BATCH * NB), 256, 0, stream>>>(K, V, KF, VF, BS);
  attn_kernel<<<dim3(BATCH * NB / 2 * CHUNKS), 256, 0, stream>>>(Q, KF, VF, PART);
  merge_kernel<<<dim3(BATCH * NB * 2), 256, 0, stream>>>(PART, BS, Out);
}

// Round 17
// 57.582 us; speedup vs baseline: 1.0811x; 1.0177x over previous
//
#include <hip/hip_runtime.h>

// Banded-block sparse attention, B=4, S=4096, D=128, block=64, w=32.
// Masked scores are 0 (not -inf) -> closed-form out-of-band correction.
//
// R17 = R16 (R12 attn core: raw-2^S bf16-P softmax, V-in-LDS, 2 tiles per
// barrier period, pair-wg; merge d-half split) with CHUNKS 4 (was 8),
// KEEPING the contiguous 16-pair-per-XCD map (R15's regression was its
// stride-8 map, not CHUNKS=4; contiguous groups are balanced +-1%).
// PART halves (34.6 -> 17.3 MB; 2.2 MB/XCD -> merge reads L2-resident);
// wg prologues halve. Zigzag pair order within each XCD (0,15,1,14,..)
// mixes heavy/light wgs at 2-resident/CU (no backfill at 512 wgs).

typedef _Float16 f16;
typedef __attribute__((ext_vector_type(8))) _Float16 f16x8;
typedef __attribute__((ext_vector_type(4))) _Float16 f16x4;
typedef __attribute__((ext_vector_type(4))) float f32x4;
typedef __attribute__((ext_vector_type(8))) short short8;
typedef __attribute__((ext_vector_type(4))) unsigned short u16x4;
typedef __attribute__((ext_vector_type(8))) unsigned short u16x8;

#define MFMA16(a, b, c) __builtin_amdgcn_mfma_f32_16x16x32_f16((a), (b), (c), 0, 0, 0)
#define MFMABF(a, b, c) __builtin_amdgcn_mfma_f32_16x16x32_bf16((a), (b), (c), 0, 0, 0)

#define BATCH 4
#define SEQ   4096
#define DIM   128
#define NB    64
#define WBAND 32
#define LOG2E 1.44269504088896f
#define TSTR  72

#define TILE  16384   // one K or V tile in fragment order: 16 frags x 64 lanes x 16B
#define CHUNKS 4
#define PART_STRIDE 16896  // 16KB o (f16 [2 qh][8 slot][64 lane][16B]) + 512B (m,l)

// LDS slots: KA@0, KB@16384, VA@32768, VB@49152
#define KA_OFF 0
#define KB_OFF 16384
#define VA_OFF 32768
#define VB_OFF 49152

#define WAIT0 asm volatile("s_waitcnt vmcnt(0)" ::: "memory")

__device__ __forceinline__ void gl16(const char* g, char* l) {
  __builtin_amdgcn_global_load_lds(
      (const __attribute__((address_space(1))) void*)g,
      (__attribute__((address_space(3))) void*)l, 16, 0, 0);
}

__device__ __forceinline__ unsigned int pk_bf16(float a, float b) {
  unsigned int r;
  asm("v_cvt_pk_bf16_f32 %0, %1, %2" : "=v"(r) : "v"(a), "v"(b));
  return r;  // lo16 = bf16(a), hi16 = bf16(b)
}

__device__ __forceinline__ unsigned short f2bf(float x) {  // RTN f32->bf16
  unsigned int u = __float_as_uint(x);
  u += 0x7FFFu + ((u >> 16) & 1u);
  return (unsigned short)(u >> 16);
}

// ---------------------------------------------------------------------------
// Packs K (f16) and V (bf16) into MFMA fragment order, plus V column sums BS.
// KF frag(ks,jt), lane l: K[s0 + jt*16 + (l&15)][ks*32 + (l>>4)*8 + e]
// VF frag(ks2,nt), lane l: V[s0 + ks2*32 + (e>>2)*16 + ((l>>4)&3)*4 + (e&3)]
//                           [nt*16 + (l&15)]   (pi-permuted contraction rows)
__global__ __launch_bounds__(256) void convert_kernel(
    const float* __restrict__ K, const float* __restrict__ V,
    f16* __restrict__ KF, unsigned short* __restrict__ VF,
    float* __restrict__ BS) {
  __shared__ unsigned short T[128 * TSTR];  // bf16 bits
  const int blk = blockIdx.x;
  const int b = blk >> 6, jb = blk & 63;
  const int s0 = jb * 64;
  const int t = threadIdx.x;

  // V -> T (d-major transpose, bf16)
#pragma unroll
  for (int i = 0; i < 8; ++i) {
    int idx = t + i * 256;
    int row = idx >> 5;
    int c4 = (idx & 31) * 4;
    float4 v = *(const float4*)(V + (size_t)(b * SEQ + s0 + row) * DIM + c4);
    T[(c4 + 0) * TSTR + row] = f2bf(v.x);
    T[(c4 + 1) * TSTR + row] = f2bf(v.y);
    T[(c4 + 2) * TSTR + row] = f2bf(v.z);
    T[(c4 + 3) * TSTR + row] = f2bf(v.w);
  }

  // KF fragments (f16, no LDS needed)
  char* kt = (char*)KF + (size_t)blk * TILE;
#pragma unroll
  for (int i = 0; i < 4; ++i) {
    int idx = t + i * 256;           // frag*64 + lane
    int frag = idx >> 6, lane = idx & 63;
    int ks = frag >> 2, jt = frag & 3;
    int row = jt * 16 + (lane & 15);
    int d0 = ks * 32 + (lane >> 4) * 8;
    const float* src = K + ((size_t)(b * SEQ + s0 + row)) * DIM + d0;
    float4 a = *(const float4*)src;
    float4 d = *(const float4*)(src + 4);
    f16x8 h = {(f16)a.x, (f16)a.y, (f16)a.z, (f16)a.w,
               (f16)d.x, (f16)d.y, (f16)d.z, (f16)d.w};
    *(f16x8*)(kt + idx * 16) = h;
  }
  __syncthreads();

  // VF fragments (bf16) with pi row-permutation, gathered from T
  char* vt = (char*)VF + (size_t)blk * TILE;
#pragma unroll
  for (int i = 0; i < 4; ++i) {
    int idx = t + i * 256;
    int frag = idx >> 6, lane = idx & 63;
    int ks2 = frag >> 3, nt = frag & 7;
    int d = nt * 16 + (lane & 15);
    int k0 = ks2 * 32 + ((lane >> 4) & 3) * 4;
    u16x4 x = *(const u16x4*)(T + d * TSTR + k0);
    u16x4 y = *(const u16x4*)(T + d * TSTR + k0 + 16);
    u16x8 h = {x[0], x[1], x[2], x[3], y[0], y[1], y[2], y[3]};
    *(u16x8*)(vt + idx * 16) = h;
  }

  if (t < 128) {
    float s = 0.f;
    for (int k = 0; k < 64; ++k)
      s += __uint_as_float(((unsigned int)T[t * TSTR + k]) << 16);
    BS[(b * NB + jb) * DIM + t] = s;
  }
}

// ---------------------------------------------------------------------------
// Pair-wg attention; 2 tiles per barrier period, single-buffered 64KB group.
__global__ __launch_bounds__(256, 2) void attn_kernel(
    const float* __restrict__ Q, const f16* __restrict__ KF,
    const unsigned short* __restrict__ VF, char* __restrict__ PART) {
  __shared__ __align__(16) char smem[65536];

  const int id = blockIdx.x;
  // contiguous 16-pair band per XCD (L2 locality, balanced +-1%);
  // zigzag pair order within the XCD mixes heavy/light wgs at 2/CU.
  const int xcd = id & 7;
  const int rr = id >> 3;             // 0..63
  const int ck = rr >> 4;             // 0..3
  const int gs = rr & 15;
  const int zg = (gs & 1) ? (15 - (gs >> 1)) : (gs >> 1);
  const int pair = xcd * 16 + zg;     // 0..127
  const int b = pair >> 5, p = pair & 31;

  const int t = threadIdx.x;
  const int w = t >> 6, l = t & 63, lg = l >> 4, ll = l & 15;
  const int half = w >> 1, qh = w & 1;   // wave -> (block-in-pair, q-half)
  const int myib = p * 2 + half;

  const int jloU = max(0, p * 2 - WBAND);
  const int jhiU = min(NB, p * 2 + 1 + WBAND);
  const int lenU = jhiU - jloU;            // 33..64
  const int base = lenU >> 2, rem = lenU & 3;
  const int j0 = jloU + ck * base + min(ck, rem);
  const int nloc = base + (ck < rem ? 1 : 0);   // 8..16, never empty
  const int mylo = max(0, myib - WBAND);
  const int myhi = min(NB, myib + WBAND);

  // Q fragments (pre-scaled by log2 e), loaded f32 direct from global.
  f16x8 qf[2][4];
#pragma unroll
  for (int s = 0; s < 2; ++s) {
    const float* qrow =
        Q + ((size_t)(b * SEQ + myib * 64 + qh * 32 + s * 16 + ll)) * DIM;
#pragma unroll
    for (int ks = 0; ks < 4; ++ks) {
      int d0 = ks * 32 + lg * 8;
      float4 a = *(const float4*)(qrow + d0);
      float4 cc = *(const float4*)(qrow + d0 + 4);
      float vv[8] = {a.x, a.y, a.z, a.w, cc.x, cc.y, cc.z, cc.w};
#pragma unroll
      for (int e = 0; e < 8; ++e) qf[s][ks][e] = (f16)(vv[e] * LOG2E);
    }
  }

  float ell[2] = {0.f, 0.f};  // per-lane partial row sums of 2^S (raw scale)
  f32x4 o[2][8];
#pragma unroll
  for (int s = 0; s < 2; ++s)
#pragma unroll
    for (int nt = 0; nt < 8; ++nt) o[s][nt] = (f32x4){0.f, 0.f, 0.f, 0.f};

  // stage group g: tiles j0+2g (A slots) and j0+2g+1 (B slots, if valid)
  auto stage_group = [&](int g) {
    const int jA = j0 + 2 * g;
    {
      const char* kg = (const char*)KF + ((size_t)(b * NB + jA)) * TILE + t * 16;
      const char* vg = (const char*)VF + ((size_t)(b * NB + jA)) * TILE + t * 16;
#pragma unroll
      for (int i = 0; i < 4; ++i) gl16(kg + i * 4096, smem + KA_OFF + t * 16 + i * 4096);
#pragma unroll
      for (int i = 0; i < 4; ++i) gl16(vg + i * 4096, smem + VA_OFF + t * 16 + i * 4096);
    }
    if (2 * g + 1 < nloc) {
      const int jB = jA + 1;
      const char* kg = (const char*)KF + ((size_t)(b * NB + jB)) * TILE + t * 16;
      const char* vg = (const char*)VF + ((size_t)(b * NB + jB)) * TILE + t * 16;
#pragma unroll
      for (int i = 0; i < 4; ++i) gl16(kg + i * 4096, smem + KB_OFF + t * 16 + i * 4096);
#pragma unroll
      for (int i = 0; i < 4; ++i) gl16(vg + i * 4096, smem + VB_OFF + t * 16 + i * 4096);
    }
  };

  // one tile visit: QK^T + raw-exp2 P (bf16) + PV  -- no softmax state
  auto compute = [&](int j, const char* kb, const char* vb) {
    if (j < mylo || j >= myhi) return;  // wave-uniform

    // ---- QK^T (swapped, f16): sacc[s][jt][r] = S[q][key = jt*16+lg*4+r]
    f32x4 sacc[2][4];
#pragma unroll
    for (int s = 0; s < 2; ++s)
#pragma unroll
      for (int jt = 0; jt < 4; ++jt) sacc[s][jt] = (f32x4){0.f, 0.f, 0.f, 0.f};

    __builtin_amdgcn_s_setprio(1);
#pragma unroll
    for (int ks = 0; ks < 4; ++ks) {
#pragma unroll
      for (int jt = 0; jt < 4; ++jt) {
        f16x8 kf = *(const f16x8*)(kb + (ks * 4 + jt) * 1024 + l * 16);
        sacc[0][jt] = MFMA16(kf, qf[0][ks], sacc[0][jt]);
        sacc[1][jt] = MFMA16(kf, qf[1][ks], sacc[1][jt]);
      }
    }
    __builtin_amdgcn_s_setprio(0);

    // ---- P = 2^S raw, packed to bf16 (lane-local; pi-V ordering)
    short8 pa[2][2];
#pragma unroll
    for (int s = 0; s < 2; ++s) {
      float rsum = 0.f;
#pragma unroll
      for (int ks2 = 0; ks2 < 2; ++ks2) {
        float pe[8];
#pragma unroll
        for (int u = 0; u < 2; ++u)
#pragma unroll
          for (int r4 = 0; r4 < 4; ++r4) {
            float pv = __builtin_amdgcn_exp2f(sacc[s][ks2 * 2 + u][r4]);
            rsum += pv;
            pe[u * 4 + r4] = pv;
          }
        union { unsigned int w2[4]; short8 v; } pk;
#pragma unroll
        for (int h2 = 0; h2 < 4; ++h2)
          pk.w2[h2] = pk_bf16(pe[h2 * 2], pe[h2 * 2 + 1]);
        pa[s][ks2] = pk.v;
      }
      ell[s] += rsum;
    }

    // ---- PV (bf16): B = pi-permuted V fragments from LDS
    __builtin_amdgcn_s_setprio(1);
#pragma unroll
    for (int ks2 = 0; ks2 < 2; ++ks2) {
#pragma unroll
      for (int nt = 0; nt < 8; ++nt) {
        short8 vbf = *(const short8*)(vb + (ks2 * 8 + nt) * 1024 + l * 16);
        o[0][nt] = MFMABF(pa[0][ks2], vbf, o[0][nt]);
        o[1][nt] = MFMABF(pa[1][ks2], vbf, o[1][nt]);
      }
    }
    __builtin_amdgcn_s_setprio(0);
  };

  const int ng = (nloc + 1) >> 1;
  stage_group(0);
  for (int g = 0; g < ng; ++g) {
    WAIT0;             // own gl16s of group g complete
    __syncthreads();   // all waves' LDS writes visible; buffer handoff

    compute(j0 + 2 * g, smem + KA_OFF, smem + VA_OFF);
    if (2 * g + 1 < nloc)
      compute(j0 + 2 * g + 1, smem + KB_OFF, smem + VB_OFF);

    __syncthreads();   // everyone done reading group g
    if (g + 1 < ng) stage_group(g + 1);
  }

  // finalize per-row sums across lg lanes (once per chunk)
#pragma unroll
  for (int s = 0; s < 2; ++s) {
    ell[s] += __shfl_xor(ell[s], 16);
    ell[s] += __shfl_xor(ell[s], 32);
  }

  // normalize o by per-row 1/ell so the f16 PART store stays in range;
  // broadcast rinv from q-row lanes (ll) to o-row layout (lg*4+r)
  float sb[2][4];
#pragma unroll
  for (int s = 0; s < 2; ++s) {
    float rinv = 1.f / ell[s];
#pragma unroll
    for (int r4 = 0; r4 < 4; ++r4) sb[s][r4] = __shfl(rinv, lg * 4 + r4);
  }

  // partial store, coalesced 16B/lane: [qh][slot=s*4+g][lane][16B]
  char* pb = PART + ((size_t)((pair * CHUNKS + ck) * 2 + half)) * PART_STRIDE;
#pragma unroll
  for (int s = 0; s < 2; ++s)
#pragma unroll
    for (int g = 0; g < 4; ++g) {
      f16x8 hh;
#pragma unroll
      for (int r4 = 0; r4 < 4; ++r4) {
        hh[r4] = (f16)(o[s][2 * g][r4] * sb[s][r4]);
        hh[4 + r4] = (f16)(o[s][2 * g + 1][r4] * sb[s][r4]);
      }
      *(f16x8*)(pb + qh * 8192 + ((s * 4 + g) * 64 + l) * 16) = hh;
    }
  if (lg == 0) {
#pragma unroll
    for (int s = 0; s < 2; ++s)
      *(float2*)(pb + 16384 + (qh * 32 + s * 16 + ll) * 8) =
          make_float2(0.f, ell[s]);
  }
}

// ---------------------------------------------------------------------------
// Merge: weighted sum of chunk partials (w_k = ell_k, raw-2^S scale) +
// out-of-band term with weight 1 per entry. Split by d-half: grid 512,
// wg = (pair, half, dh); each wg reads slots {s*4 + dh*2 + g} only.
__global__ __launch_bounds__(256) void merge_kernel(
    const char* __restrict__ PART, const float* __restrict__ BS,
    float* __restrict__ Out) {
  __shared__ float VoutS[DIM];
  __shared__ float mlS[CHUNKS][64][2];

  const int id = blockIdx.x;
  const int lin = (id & 7) * 64 + (id >> 3);  // XCD-contiguous pairs (match attn)
  const int pair = lin >> 2;
  const int half = (lin >> 1) & 1;
  const int dh = lin & 1;
  const int b = pair >> 5;
  const int ib = (pair & 31) * 2 + half;
  const int t = threadIdx.x;
  const int l = t & 63, lg = (t >> 4) & 3, ll = t & 15;
  const int sub = (t >> 6) & 1, qh = t >> 7;

  const int jlo = max(0, ib - WBAND);
  const int jhi = min(NB, ib + WBAND);
  const float cnt_out = (float)(SEQ - (jhi - jlo) * 64);

  if (t < DIM) {
    float s = 0.f;
    for (int j = 0; j < jlo; ++j) s += BS[(b * NB + j) * DIM + t];
    for (int j = jhi; j < NB; ++j) s += BS[(b * NB + j) * DIM + t];
    VoutS[t] = s;
  }

  const size_t pb0 = ((size_t)(pair * CHUNKS * 2 + half)) * PART_STRIDE;
  for (int i = t; i < CHUNKS * 64; i += 256) {
    int k = i >> 6, row = i & 63;
    *(float2*)&mlS[k][row][0] = *(const float2*)(
        PART + pb0 + (size_t)k * 2 * PART_STRIDE + 16384 + row * 8);
  }
  __syncthreads();

  float aw[4][CHUNKS], inv[4];
#pragma unroll
  for (int r = 0; r < 4; ++r) {
    int row = qh * 32 + sub * 16 + lg * 4 + r;
    float den = cnt_out;
#pragma unroll
    for (int k = 0; k < CHUNKS; ++k) {
      aw[r][k] = mlS[k][row][1];
      den += aw[r][k];
    }
    inv[r] = 1.f / den;
  }

  float acc[4][4];
#pragma unroll
  for (int n2 = 0; n2 < 4; ++n2)
#pragma unroll
    for (int r = 0; r < 4; ++r) acc[n2][r] = 0.f;

  for (int k = 0; k < CHUNKS; ++k) {
    const char* oc = PART + pb0 + (size_t)k * 2 * PART_STRIDE + qh * 8192;
#pragma unroll
    for (int g = 0; g < 2; ++g) {
      int slot = sub * 4 + dh * 2 + g;
      f16x8 h = *(const f16x8*)(oc + (slot * 64 + l) * 16);
#pragma unroll
      for (int r = 0; r < 4; ++r) {
        acc[2 * g][r] += aw[r][k] * (float)h[r];
        acc[2 * g + 1][r] += aw[r][k] * (float)h[4 + r];
      }
    }
  }

  const int q0 = ib * 64;
#pragma unroll
  for (int n2 = 0; n2 < 4; ++n2) {
    int nt = dh * 4 + n2;            // stored slot g covers nt = 2g, 2g+1
    int col = nt * 16 + ll;
    float vout = VoutS[col];
#pragma unroll
    for (int r = 0; r < 4; ++r) {
      int row = qh * 32 + sub * 16 + lg * 4 + r;
      Out[((size_t)(b * SEQ + q0 + row)) * DIM + col] =
          (acc[n2][r] + vout) * inv[r];
    }
  }
}

// ---------------------------------------------------------------------------
extern "C" void kernel_launch(void* const* d_in, const int* in_sizes, int n_in,
                              void* d_out, int out_size, void* d_ws, size_t ws_size,
                              hipStream_t stream) {
  const float* Q = (const float*)d_in[0];
  const float* K = (const float*)d_in[1];
  const float* V = (const float*)d_in[2];
  float* Out = (float*)d_out;

  char* ws = (char*)d_ws;
  f16* KF = (f16*)ws;                                   // 4 MB
  unsigned short* VF = (unsigned short*)(ws + (size_t)BATCH * NB * TILE);  // 4 MB
  float* BS = (float*)(ws + 2 * (size_t)BATCH * NB * TILE);  // 128 KB
  char* PART = ws + 2 * (size_t)BATCH * NB * TILE + (size_t)BATCH * NB * DIM * 4;

  convert_kernel<<<dim3(BATCH * NB), 256, 0, stream>>>(K, V, KF, VF, BS);
  attn_kernel<<<dim3(BATCH * NB / 2 * CHUNKS), 256, 0, stream>>>(Q, KF, VF, PART);
  merge_kernel<<<dim3(BATCH * NB * 2), 256, 0, stream>>>(PART, BS, Out);
}

// Round 18
// 56.946 us; speedup vs baseline: 1.0931x; 1.0112x over previous
//
#include <hip/hip_runtime.h>

// Banded-block sparse attention, B=4, S=4096, D=128, block=64, w=32.
// Masked scores are 0 (not -inf) -> closed-form out-of-band correction.
//
// R18 = R17 attn+merge VERBATIM (raw-2^S bf16-P softmax, V-in-LDS, 2 tiles
// per barrier period, pair-wg, CHUNKS=4, contiguous-band XCD map + zigzag;
// merge d-half split) + convert kernel split by d-half: grid 256 -> 512
// (2 wg/CU), each wg converts 64 of 128 d-columns (V-loads, T-transpose,
// KF ks-half, VF nt-half, BS sums all partition cleanly by d). Halves the
// per-wg critical path of the convert stage (~6us -> ~4us).

typedef _Float16 f16;
typedef __attribute__((ext_vector_type(8))) _Float16 f16x8;
typedef __attribute__((ext_vector_type(4))) _Float16 f16x4;
typedef __attribute__((ext_vector_type(4))) float f32x4;
typedef __attribute__((ext_vector_type(8))) short short8;
typedef __attribute__((ext_vector_type(4))) unsigned short u16x4;
typedef __attribute__((ext_vector_type(8))) unsigned short u16x8;

#define MFMA16(a, b, c) __builtin_amdgcn_mfma_f32_16x16x32_f16((a), (b), (c), 0, 0, 0)
#define MFMABF(a, b, c) __builtin_amdgcn_mfma_f32_16x16x32_bf16((a), (b), (c), 0, 0, 0)

#define BATCH 4
#define SEQ   4096
#define DIM   128
#define NB    64
#define WBAND 32
#define LOG2E 1.44269504088896f
#define TSTR  72

#define TILE  16384   // one K or V tile in fragment order: 16 frags x 64 lanes x 16B
#define CHUNKS 4
#define PART_STRIDE 16896  // 16KB o (f16 [2 qh][8 slot][64 lane][16B]) + 512B (m,l)

// LDS slots: KA@0, KB@16384, VA@32768, VB@49152
#define KA_OFF 0
#define KB_OFF 16384
#define VA_OFF 32768
#define VB_OFF 49152

#define WAIT0 asm volatile("s_waitcnt vmcnt(0)" ::: "memory")

__device__ __forceinline__ void gl16(const char* g, char* l) {
  __builtin_amdgcn_global_load_lds(
      (const __attribute__((address_space(1))) void*)g,
      (__attribute__((address_space(3))) void*)l, 16, 0, 0);
}

__device__ __forceinline__ unsigned int pk_bf16(float a, float b) {
  unsigned int r;
  asm("v_cvt_pk_bf16_f32 %0, %1, %2" : "=v"(r) : "v"(a), "v"(b));
  return r;  // lo16 = bf16(a), hi16 = bf16(b)
}

__device__ __forceinline__ unsigned short f2bf(float x) {  // RTN f32->bf16
  unsigned int u = __float_as_uint(x);
  u += 0x7FFFu + ((u >> 16) & 1u);
  return (unsigned short)(u >> 16);
}

// ---------------------------------------------------------------------------
// Packs K (f16) and V (bf16) into MFMA fragment order, plus V column sums BS.
// Split by d-half: wg = (blk, dh); dh covers d in [dh*64, dh*64+64).
// KF frag(ks,jt), lane l: K[s0 + jt*16 + (l&15)][ks*32 + (l>>4)*8 + e]
//   -> dh handles ks in {dh*2, dh*2+1} (frags ks*4+jt).
// VF frag(ks2,nt), lane l: V[s0 + pi(ks2,lg,e)][nt*16 + (l&15)]
//   -> dh handles nt in [dh*4, dh*4+4) (frags ks2*8+nt).
__global__ __launch_bounds__(256) void convert_kernel(
    const float* __restrict__ K, const float* __restrict__ V,
    f16* __restrict__ KF, unsigned short* __restrict__ VF,
    float* __restrict__ BS) {
  __shared__ unsigned short T[64 * TSTR];  // bf16 bits, this wg's 64 d-rows
  const int id = blockIdx.x;
  const int blk = id >> 1, dh = id & 1;
  const int b = blk >> 6, jb = blk & 63;
  const int s0 = jb * 64;
  const int d0g = dh * 64;             // global d base for this wg
  const int t = threadIdx.x;

  // V -> T (d-major transpose, bf16): 64 seq-rows x 64 d-cols
#pragma unroll
  for (int i = 0; i < 4; ++i) {
    int idx = t + i * 256;
    int row = idx >> 4;                // 0..63 (seq)
    int c4 = (idx & 15) * 4;           // 0..60 (local d)
    float4 v = *(const float4*)(V + (size_t)(b * SEQ + s0 + row) * DIM + d0g + c4);
    T[(c4 + 0) * TSTR + row] = f2bf(v.x);
    T[(c4 + 1) * TSTR + row] = f2bf(v.y);
    T[(c4 + 2) * TSTR + row] = f2bf(v.z);
    T[(c4 + 3) * TSTR + row] = f2bf(v.w);
  }

  // KF fragments (f16, no LDS needed): frags ks = dh*2 + (0,1), jt = 0..3
  char* kt = (char*)KF + (size_t)blk * TILE;
#pragma unroll
  for (int i = 0; i < 2; ++i) {
    int idx = t + i * 256;             // local frag*64 + lane, frag 0..7
    int lfr = idx >> 6, lane = idx & 63;
    int ks = dh * 2 + (lfr >> 2), jt = lfr & 3;
    int frag = ks * 4 + jt;
    int row = jt * 16 + (lane & 15);
    int d0 = ks * 32 + (lane >> 4) * 8;
    const float* src = K + ((size_t)(b * SEQ + s0 + row)) * DIM + d0;
    float4 a = *(const float4*)src;
    float4 d = *(const float4*)(src + 4);
    f16x8 h = {(f16)a.x, (f16)a.y, (f16)a.z, (f16)a.w,
               (f16)d.x, (f16)d.y, (f16)d.z, (f16)d.w};
    *(f16x8*)(kt + (frag * 64 + lane) * 16) = h;
  }
  __syncthreads();

  // VF fragments (bf16) with pi row-permutation, gathered from T:
  // frags ks2 = 0..1, nt = dh*4 + (0..3)
  char* vt = (char*)VF + (size_t)blk * TILE;
#pragma unroll
  for (int i = 0; i < 2; ++i) {
    int idx = t + i * 256;
    int lfr = idx >> 6, lane = idx & 63;
    int ks2 = lfr >> 2;
    int nt = dh * 4 + (lfr & 3);
    int frag = ks2 * 8 + nt;
    int dl = (nt * 16 + (lane & 15)) - d0g;   // local d row in T
    int k0 = ks2 * 32 + ((lane >> 4) & 3) * 4;
    u16x4 x = *(const u16x4*)(T + dl * TSTR + k0);
    u16x4 y = *(const u16x4*)(T + dl * TSTR + k0 + 16);
    u16x8 h = {x[0], x[1], x[2], x[3], y[0], y[1], y[2], y[3]};
    *(u16x8*)(vt + (frag * 64 + lane) * 16) = h;
  }

  if (t < 64) {
    float s = 0.f;
    for (int k = 0; k < 64; ++k)
      s += __uint_as_float(((unsigned int)T[t * TSTR + k]) << 16);
    BS[(b * NB + jb) * DIM + d0g + t] = s;
  }
}

// ---------------------------------------------------------------------------
// Pair-wg attention; 2 tiles per barrier period, single-buffered 64KB group.
// (R17 verbatim)
__global__ __launch_bounds__(256, 2) void attn_kernel(
    const float* __restrict__ Q, const f16* __restrict__ KF,
    const unsigned short* __restrict__ VF, char* __restrict__ PART) {
  __shared__ __align__(16) char smem[65536];

  const int id = blockIdx.x;
  // contiguous 16-pair band per XCD (L2 locality, balanced +-1%);
  // zigzag pair order within the XCD mixes heavy/light wgs at 2/CU.
  const int xcd = id & 7;
  const int rr = id >> 3;             // 0..63
  const int ck = rr >> 4;             // 0..3
  const int gs = rr & 15;
  const int zg = (gs & 1) ? (15 - (gs >> 1)) : (gs >> 1);
  const int pair = xcd * 16 + zg;     // 0..127
  const int b = pair >> 5, p = pair & 31;

  const int t = threadIdx.x;
  const int w = t >> 6, l = t & 63, lg = l >> 4, ll = l & 15;
  const int half = w >> 1, qh = w & 1;   // wave -> (block-in-pair, q-half)
  const int myib = p * 2 + half;

  const int jloU = max(0, p * 2 - WBAND);
  const int jhiU = min(NB, p * 2 + 1 + WBAND);
  const int lenU = jhiU - jloU;            // 33..64
  const int base = lenU >> 2, rem = lenU & 3;
  const int j0 = jloU + ck * base + min(ck, rem);
  const int nloc = base + (ck < rem ? 1 : 0);   // 8..16, never empty
  const int mylo = max(0, myib - WBAND);
  const int myhi = min(NB, myib + WBAND);

  // Q fragments (pre-scaled by log2 e), loaded f32 direct from global.
  f16x8 qf[2][4];
#pragma unroll
  for (int s = 0; s < 2; ++s) {
    const float* qrow =
        Q + ((size_t)(b * SEQ + myib * 64 + qh * 32 + s * 16 + ll)) * DIM;
#pragma unroll
    for (int ks = 0; ks < 4; ++ks) {
      int d0 = ks * 32 + lg * 8;
      float4 a = *(const float4*)(qrow + d0);
      float4 cc = *(const float4*)(qrow + d0 + 4);
      float vv[8] = {a.x, a.y, a.z, a.w, cc.x, cc.y, cc.z, cc.w};
#pragma unroll
      for (int e = 0; e < 8; ++e) qf[s][ks][e] = (f16)(vv[e] * LOG2E);
    }
  }

  float ell[2] = {0.f, 0.f};  // per-lane partial row sums of 2^S (raw scale)
  f32x4 o[2][8];
#pragma unroll
  for (int s = 0; s < 2; ++s)
#pragma unroll
    for (int nt = 0; nt < 8; ++nt) o[s][nt] = (f32x4){0.f, 0.f, 0.f, 0.f};

  // stage group g: tiles j0+2g (A slots) and j0+2g+1 (B slots, if valid)
  auto stage_group = [&](int g) {
    const int jA = j0 + 2 * g;
    {
      const char* kg = (const char*)KF + ((size_t)(b * NB + jA)) * TILE + t * 16;
      const char* vg = (const char*)VF + ((size_t)(b * NB + jA)) * TILE + t * 16;
#pragma unroll
      for (int i = 0; i < 4; ++i) gl16(kg + i * 4096, smem + KA_OFF + t * 16 + i * 4096);
#pragma unroll
      for (int i = 0; i < 4; ++i) gl16(vg + i * 4096, smem + VA_OFF + t * 16 + i * 4096);
    }
    if (2 * g + 1 < nloc) {
      const int jB = jA + 1;
      const char* kg = (const char*)KF + ((size_t)(b * NB + jB)) * TILE + t * 16;
      const char* vg = (const char*)VF + ((size_t)(b * NB + jB)) * TILE + t * 16;
#pragma unroll
      for (int i = 0; i < 4; ++i) gl16(kg + i * 4096, smem + KB_OFF + t * 16 + i * 4096);
#pragma unroll
      for (int i = 0; i < 4; ++i) gl16(vg + i * 4096, smem + VB_OFF + t * 16 + i * 4096);
    }
  };

  // one tile visit: QK^T + raw-exp2 P (bf16) + PV  -- no softmax state
  auto compute = [&](int j, const char* kb, const char* vb) {
    if (j < mylo || j >= myhi) return;  // wave-uniform

    // ---- QK^T (swapped, f16): sacc[s][jt][r] = S[q][key = jt*16+lg*4+r]
    f32x4 sacc[2][4];
#pragma unroll
    for (int s = 0; s < 2; ++s)
#pragma unroll
      for (int jt = 0; jt < 4; ++jt) sacc[s][jt] = (f32x4){0.f, 0.f, 0.f, 0.f};

    __builtin_amdgcn_s_setprio(1);
#pragma unroll
    for (int ks = 0; ks < 4; ++ks) {
#pragma unroll
      for (int jt = 0; jt < 4; ++jt) {
        f16x8 kf = *(const f16x8*)(kb + (ks * 4 + jt) * 1024 + l * 16);
        sacc[0][jt] = MFMA16(kf, qf[0][ks], sacc[0][jt]);
        sacc[1][jt] = MFMA16(kf, qf[1][ks], sacc[1][jt]);
      }
    }
    __builtin_amdgcn_s_setprio(0);

    // ---- P = 2^S raw, packed to bf16 (lane-local; pi-V ordering)
    short8 pa[2][2];
#pragma unroll
    for (int s = 0; s < 2; ++s) {
      float rsum = 0.f;
#pragma unroll
      for (int ks2 = 0; ks2 < 2; ++ks2) {
        float pe[8];
#pragma unroll
        for (int u = 0; u < 2; ++u)
#pragma unroll
          for (int r4 = 0; r4 < 4; ++r4) {
            float pv = __builtin_amdgcn_exp2f(sacc[s][ks2 * 2 + u][r4]);
            rsum += pv;
            pe[u * 4 + r4] = pv;
          }
        union { unsigned int w2[4]; short8 v; } pk;
#pragma unroll
        for (int h2 = 0; h2 < 4; ++h2)
          pk.w2[h2] = pk_bf16(pe[h2 * 2], pe[h2 * 2 + 1]);
        pa[s][ks2] = pk.v;
      }
      ell[s] += rsum;
    }

    // ---- PV (bf16): B = pi-permuted V fragments from LDS
    __builtin_amdgcn_s_setprio(1);
#pragma unroll
    for (int ks2 = 0; ks2 < 2; ++ks2) {
#pragma unroll
      for (int nt = 0; nt < 8; ++nt) {
        short8 vbf = *(const short8*)(vb + (ks2 * 8 + nt) * 1024 + l * 16);
        o[0][nt] = MFMABF(pa[0][ks2], vbf, o[0][nt]);
        o[1][nt] = MFMABF(pa[1][ks2], vbf, o[1][nt]);
      }
    }
    __builtin_amdgcn_s_setprio(0);
  };

  const int ng = (nloc + 1) >> 1;
  stage_group(0);
  for (int g = 0; g < ng; ++g) {
    WAIT0;             // own gl16s of group g complete
    __syncthreads();   // all waves' LDS writes visible; buffer handoff

    compute(j0 + 2 * g, smem + KA_OFF, smem + VA_OFF);
    if (2 * g + 1 < nloc)
      compute(j0 + 2 * g + 1, smem + KB_OFF, smem + VB_OFF);

    __syncthreads();   // everyone done reading group g
    if (g + 1 < ng) stage_group(g + 1);
  }

  // finalize per-row sums across lg lanes (once per chunk)
#pragma unroll
  for (int s = 0; s < 2; ++s) {
    ell[s] += __shfl_xor(ell[s], 16);
    ell[s] += __shfl_xor(ell[s], 32);
  }

  // normalize o by per-row 1/ell so the f16 PART store stays in range;
  // broadcast rinv from q-row lanes (ll) to o-row layout (lg*4+r)
  float sb[2][4];
#pragma unroll
  for (int s = 0; s < 2; ++s) {
    float rinv = 1.f / ell[s];
#pragma unroll
    for (int r4 = 0; r4 < 4; ++r4) sb[s][r4] = __shfl(rinv, lg * 4 + r4);
  }

  // partial store, coalesced 16B/lane: [qh][slot=s*4+g][lane][16B]
  char* pb = PART + ((size_t)((pair * CHUNKS + ck) * 2 + half)) * PART_STRIDE;
#pragma unroll
  for (int s = 0; s < 2; ++s)
#pragma unroll
    for (int g = 0; g < 4; ++g) {
      f16x8 hh;
#pragma unroll
      for (int r4 = 0; r4 < 4; ++r4) {
        hh[r4] = (f16)(o[s][2 * g][r4] * sb[s][r4]);
        hh[4 + r4] = (f16)(o[s][2 * g + 1][r4] * sb[s][r4]);
      }
      *(f16x8*)(pb + qh * 8192 + ((s * 4 + g) * 64 + l) * 16) = hh;
    }
  if (lg == 0) {
#pragma unroll
    for (int s = 0; s < 2; ++s)
      *(float2*)(pb + 16384 + (qh * 32 + s * 16 + ll) * 8) =
          make_float2(0.f, ell[s]);
  }
}

// ---------------------------------------------------------------------------
// Merge: weighted sum of chunk partials (w_k = ell_k, raw-2^S scale) +
// out-of-band term with weight 1 per entry. Split by d-half: grid 512,
// wg = (pair, half, dh); each wg reads slots {s*4 + dh*2 + g} only.
__global__ __launch_bounds__(256) void merge_kernel(
    const char* __restrict__ PART, const float* __restrict__ BS,
    float* __restrict__ Out) {
  __shared__ float VoutS[DIM];
  __shared__ float mlS[CHUNKS][64][2];

  const int id = blockIdx.x;
  const int lin = (id & 7) * 64 + (id >> 3);  // XCD-contiguous pairs (match attn)
  const int pair = lin >> 2;
  const int half = (lin >> 1) & 1;
  const int dh = lin & 1;
  const int b = pair >> 5;
  const int ib = (pair & 31) * 2 + half;
  const int t = threadIdx.x;
  const int l = t & 63, lg = (t >> 4) & 3, ll = t & 15;
  const int sub = (t >> 6) & 1, qh = t >> 7;

  const int jlo = max(0, ib - WBAND);
  const int jhi = min(NB, ib + WBAND);
  const float cnt_out = (float)(SEQ - (jhi - jlo) * 64);

  if (t < DIM) {
    float s = 0.f;
    for (int j = 0; j < jlo; ++j) s += BS[(b * NB + j) * DIM + t];
    for (int j = jhi; j < NB; ++j) s += BS[(b * NB + j) * DIM + t];
    VoutS[t] = s;
  }

  const size_t pb0 = ((size_t)(pair * CHUNKS * 2 + half)) * PART_STRIDE;
  for (int i = t; i < CHUNKS * 64; i += 256) {
    int k = i >> 6, row = i & 63;
    *(float2*)&mlS[k][row][0] = *(const float2*)(
        PART + pb0 + (size_t)k * 2 * PART_STRIDE + 16384 + row * 8);
  }
  __syncthreads();

  float aw[4][CHUNKS], inv[4];
#pragma unroll
  for (int r = 0; r < 4; ++r) {
    int row = qh * 32 + sub * 16 + lg * 4 + r;
    float den = cnt_out;
#pragma unroll
    for (int k = 0; k < CHUNKS; ++k) {
      aw[r][k] = mlS[k][row][1];
      den += aw[r][k];
    }
    inv[r] = 1.f / den;
  }

  float acc[4][4];
#pragma unroll
  for (int n2 = 0; n2 < 4; ++n2)
#pragma unroll
    for (int r = 0; r < 4; ++r) acc[n2][r] = 0.f;

  for (int k = 0; k < CHUNKS; ++k) {
    const char* oc = PART + pb0 + (size_t)k * 2 * PART_STRIDE + qh * 8192;
#pragma unroll
    for (int g = 0; g < 2; ++g) {
      int slot = sub * 4 + dh * 2 + g;
      f16x8 h = *(const f16x8*)(oc + (slot * 64 + l) * 16);
#pragma unroll
      for (int r = 0; r < 4; ++r) {
        acc[2 * g][r] += aw[r][k] * (float)h[r];
        acc[2 * g + 1][r] += aw[r][k] * (float)h[4 + r];
      }
    }
  }

  const int q0 = ib * 64;
#pragma unroll
  for (int n2 = 0; n2 < 4; ++n2) {
    int nt = dh * 4 + n2;            // stored slot g covers nt = 2g, 2g+1
    int col = nt * 16 + ll;
    float vout = VoutS[col];
#pragma unroll
    for (int r = 0; r < 4; ++r) {
      int row = qh * 32 + sub * 16 + lg * 4 + r;
      Out[((size_t)(b * SEQ + q0 + row)) * DIM + col] =
          (acc[n2][r] + vout) * inv[r];
    }
  }
}

// ---------------------------------------------------------------------------
extern "C" void kernel_launch(void* const* d_in, const int* in_sizes, int n_in,
                              void* d_out, int out_size, void* d_ws, size_t ws_size,
                              hipStream_t stream) {
  const float* Q = (const float*)d_in[0];
  const float* K = (const float*)d_in[1];
  const float* V = (const float*)d_in[2];
  float* Out = (float*)d_out;

  char* ws = (char*)d_ws;
  f16* KF = (f16*)ws;                                   // 4 MB
  unsigned short* VF = (unsigned short*)(ws + (size_t)BATCH * NB * TILE);  // 4 MB
  float* BS = (float*)(ws + 2 * (size_t)BATCH * NB * TILE);  // 128 KB
  char* PART = ws + 2 * (size_t)BATCH * NB * TILE + (size_t)BATCH * NB * DIM * 4;

  convert_kernel<<<dim3(BATCH * NB * 2), 256, 0, stream>>>(K, V, KF, VF, BS);
  attn_kernel<<<dim3(BATCH * NB / 2 * CHUNKS), 256, 0, stream>>>(Q, KF, VF, PART);
  merge_kernel<<<dim3(BATCH * NB * 2), 256, 0, stream>>>(PART, BS, Out);
}

// Round 19
// 56.270 us; speedup vs baseline: 1.1063x; 1.0120x over previous
//
#include <hip/hip_runtime.h>

// Banded-block sparse attention, B=4, S=4096, D=128, block=64, w=32.
// Masked scores are 0 (not -inf) -> closed-form out-of-band correction.
//
// R19 = R18 attn VERBATIM (raw-2^S bf16-P softmax, V-in-LDS, 2 tiles per
// barrier period, pair-wg, CHUNKS=4, contiguous-band XCD map + zigzag)
// + convert and merge pushed from d-half to d-QUARTER splits (grid 1024
// each, 4 wg/CU): pure bijective re-partitions of the verified loops.

typedef _Float16 f16;
typedef __attribute__((ext_vector_type(8))) _Float16 f16x8;
typedef __attribute__((ext_vector_type(4))) _Float16 f16x4;
typedef __attribute__((ext_vector_type(4))) float f32x4;
typedef __attribute__((ext_vector_type(8))) short short8;
typedef __attribute__((ext_vector_type(4))) unsigned short u16x4;
typedef __attribute__((ext_vector_type(8))) unsigned short u16x8;

#define MFMA16(a, b, c) __builtin_amdgcn_mfma_f32_16x16x32_f16((a), (b), (c), 0, 0, 0)
#define MFMABF(a, b, c) __builtin_amdgcn_mfma_f32_16x16x32_bf16((a), (b), (c), 0, 0, 0)

#define BATCH 4
#define SEQ   4096
#define DIM   128
#define NB    64
#define WBAND 32
#define LOG2E 1.44269504088896f
#define TSTR  72

#define TILE  16384   // one K or V tile in fragment order: 16 frags x 64 lanes x 16B
#define CHUNKS 4
#define PART_STRIDE 16896  // 16KB o (f16 [2 qh][8 slot][64 lane][16B]) + 512B (m,l)

// LDS slots: KA@0, KB@16384, VA@32768, VB@49152
#define KA_OFF 0
#define KB_OFF 16384
#define VA_OFF 32768
#define VB_OFF 49152

#define WAIT0 asm volatile("s_waitcnt vmcnt(0)" ::: "memory")

__device__ __forceinline__ void gl16(const char* g, char* l) {
  __builtin_amdgcn_global_load_lds(
      (const __attribute__((address_space(1))) void*)g,
      (__attribute__((address_space(3))) void*)l, 16, 0, 0);
}

__device__ __forceinline__ unsigned int pk_bf16(float a, float b) {
  unsigned int r;
  asm("v_cvt_pk_bf16_f32 %0, %1, %2" : "=v"(r) : "v"(a), "v"(b));
  return r;  // lo16 = bf16(a), hi16 = bf16(b)
}

__device__ __forceinline__ unsigned short f2bf(float x) {  // RTN f32->bf16
  unsigned int u = __float_as_uint(x);
  u += 0x7FFFu + ((u >> 16) & 1u);
  return (unsigned short)(u >> 16);
}

// ---------------------------------------------------------------------------
// Packs K (f16) and V (bf16) into MFMA fragment order, plus V column sums BS.
// Split by d-quarter: wg = (blk, dq); dq covers d in [dq*32, dq*32+32).
// KF: ks = dq (frags dq*4+jt).  VF: nt = dq*2 + {0,1} (frags ks2*8+nt).
__global__ __launch_bounds__(256) void convert_kernel(
    const float* __restrict__ K, const float* __restrict__ V,
    f16* __restrict__ KF, unsigned short* __restrict__ VF,
    float* __restrict__ BS) {
  __shared__ unsigned short T[32 * TSTR];  // bf16 bits, this wg's 32 d-rows
  const int id = blockIdx.x;
  const int blk = id >> 2, dq = id & 3;
  const int b = blk >> 6, jb = blk & 63;
  const int s0 = jb * 64;
  const int d0g = dq * 32;             // global d base for this wg
  const int t = threadIdx.x;

  // V -> T (d-major transpose, bf16): 64 seq-rows x 32 d-cols
#pragma unroll
  for (int i = 0; i < 2; ++i) {
    int idx = t + i * 256;
    int row = idx >> 3;                // 0..63 (seq)
    int c4 = (idx & 7) * 4;            // 0..28 (local d)
    float4 v = *(const float4*)(V + (size_t)(b * SEQ + s0 + row) * DIM + d0g + c4);
    T[(c4 + 0) * TSTR + row] = f2bf(v.x);
    T[(c4 + 1) * TSTR + row] = f2bf(v.y);
    T[(c4 + 2) * TSTR + row] = f2bf(v.z);
    T[(c4 + 3) * TSTR + row] = f2bf(v.w);
  }

  // KF fragments (f16, no LDS needed): ks = dq, jt = 0..3 (one pass)
  char* kt = (char*)KF + (size_t)blk * TILE;
  {
    int lfr = t >> 6, lane = t & 63;   // lfr = jt
    int frag = dq * 4 + lfr;
    int row = lfr * 16 + (lane & 15);
    int d0 = dq * 32 + (lane >> 4) * 8;
    const float* src = K + ((size_t)(b * SEQ + s0 + row)) * DIM + d0;
    float4 a = *(const float4*)src;
    float4 d = *(const float4*)(src + 4);
    f16x8 h = {(f16)a.x, (f16)a.y, (f16)a.z, (f16)a.w,
               (f16)d.x, (f16)d.y, (f16)d.z, (f16)d.w};
    *(f16x8*)(kt + (frag * 64 + lane) * 16) = h;
  }
  __syncthreads();

  // VF fragments (bf16) with pi row-permutation, gathered from T (one pass):
  // ks2 = 0..1, nt = dq*2 + {0,1}
  char* vt = (char*)VF + (size_t)blk * TILE;
  {
    int lfr = t >> 6, lane = t & 63;
    int ks2 = lfr >> 1;
    int nt = dq * 2 + (lfr & 1);
    int frag = ks2 * 8 + nt;
    int dl = (nt * 16 + (lane & 15)) - d0g;   // local d row in T, 0..31
    int k0 = ks2 * 32 + ((lane >> 4) & 3) * 4;
    u16x4 x = *(const u16x4*)(T + dl * TSTR + k0);
    u16x4 y = *(const u16x4*)(T + dl * TSTR + k0 + 16);
    u16x8 h = {x[0], x[1], x[2], x[3], y[0], y[1], y[2], y[3]};
    *(u16x8*)(vt + (frag * 64 + lane) * 16) = h;
  }

  if (t < 32) {
    float s = 0.f;
    for (int k = 0; k < 64; ++k)
      s += __uint_as_float(((unsigned int)T[t * TSTR + k]) << 16);
    BS[(b * NB + jb) * DIM + d0g + t] = s;
  }
}

// ---------------------------------------------------------------------------
// Pair-wg attention; 2 tiles per barrier period, single-buffered 64KB group.
// (R17/R18 verbatim)
__global__ __launch_bounds__(256, 2) void attn_kernel(
    const float* __restrict__ Q, const f16* __restrict__ KF,
    const unsigned short* __restrict__ VF, char* __restrict__ PART) {
  __shared__ __align__(16) char smem[65536];

  const int id = blockIdx.x;
  // contiguous 16-pair band per XCD (L2 locality, balanced +-1%);
  // zigzag pair order within the XCD mixes heavy/light wgs at 2/CU.
  const int xcd = id & 7;
  const int rr = id >> 3;             // 0..63
  const int ck = rr >> 4;             // 0..3
  const int gs = rr & 15;
  const int zg = (gs & 1) ? (15 - (gs >> 1)) : (gs >> 1);
  const int pair = xcd * 16 + zg;     // 0..127
  const int b = pair >> 5, p = pair & 31;

  const int t = threadIdx.x;
  const int w = t >> 6, l = t & 63, lg = l >> 4, ll = l & 15;
  const int half = w >> 1, qh = w & 1;   // wave -> (block-in-pair, q-half)
  const int myib = p * 2 + half;

  const int jloU = max(0, p * 2 - WBAND);
  const int jhiU = min(NB, p * 2 + 1 + WBAND);
  const int lenU = jhiU - jloU;            // 33..64
  const int base = lenU >> 2, rem = lenU & 3;
  const int j0 = jloU + ck * base + min(ck, rem);
  const int nloc = base + (ck < rem ? 1 : 0);   // 8..16, never empty
  const int mylo = max(0, myib - WBAND);
  const int myhi = min(NB, myib + WBAND);

  // Q fragments (pre-scaled by log2 e), loaded f32 direct from global.
  f16x8 qf[2][4];
#pragma unroll
  for (int s = 0; s < 2; ++s) {
    const float* qrow =
        Q + ((size_t)(b * SEQ + myib * 64 + qh * 32 + s * 16 + ll)) * DIM;
#pragma unroll
    for (int ks = 0; ks < 4; ++ks) {
      int d0 = ks * 32 + lg * 8;
      float4 a = *(const float4*)(qrow + d0);
      float4 cc = *(const float4*)(qrow + d0 + 4);
      float vv[8] = {a.x, a.y, a.z, a.w, cc.x, cc.y, cc.z, cc.w};
#pragma unroll
      for (int e = 0; e < 8; ++e) qf[s][ks][e] = (f16)(vv[e] * LOG2E);
    }
  }

  float ell[2] = {0.f, 0.f};  // per-lane partial row sums of 2^S (raw scale)
  f32x4 o[2][8];
#pragma unroll
  for (int s = 0; s < 2; ++s)
#pragma unroll
    for (int nt = 0; nt < 8; ++nt) o[s][nt] = (f32x4){0.f, 0.f, 0.f, 0.f};

  // stage group g: tiles j0+2g (A slots) and j0+2g+1 (B slots, if valid)
  auto stage_group = [&](int g) {
    const int jA = j0 + 2 * g;
    {
      const char* kg = (const char*)KF + ((size_t)(b * NB + jA)) * TILE + t * 16;
      const char* vg = (const char*)VF + ((size_t)(b * NB + jA)) * TILE + t * 16;
#pragma unroll
      for (int i = 0; i < 4; ++i) gl16(kg + i * 4096, smem + KA_OFF + t * 16 + i * 4096);
#pragma unroll
      for (int i = 0; i < 4; ++i) gl16(vg + i * 4096, smem + VA_OFF + t * 16 + i * 4096);
    }
    if (2 * g + 1 < nloc) {
      const int jB = jA + 1;
      const char* kg = (const char*)KF + ((size_t)(b * NB + jB)) * TILE + t * 16;
      const char* vg = (const char*)VF + ((size_t)(b * NB + jB)) * TILE + t * 16;
#pragma unroll
      for (int i = 0; i < 4; ++i) gl16(kg + i * 4096, smem + KB_OFF + t * 16 + i * 4096);
#pragma unroll
      for (int i = 0; i < 4; ++i) gl16(vg + i * 4096, smem + VB_OFF + t * 16 + i * 4096);
    }
  };

  // one tile visit: QK^T + raw-exp2 P (bf16) + PV  -- no softmax state
  auto compute = [&](int j, const char* kb, const char* vb) {
    if (j < mylo || j >= myhi) return;  // wave-uniform

    // ---- QK^T (swapped, f16): sacc[s][jt][r] = S[q][key = jt*16+lg*4+r]
    f32x4 sacc[2][4];
#pragma unroll
    for (int s = 0; s < 2; ++s)
#pragma unroll
      for (int jt = 0; jt < 4; ++jt) sacc[s][jt] = (f32x4){0.f, 0.f, 0.f, 0.f};

    __builtin_amdgcn_s_setprio(1);
#pragma unroll
    for (int ks = 0; ks < 4; ++ks) {
#pragma unroll
      for (int jt = 0; jt < 4; ++jt) {
        f16x8 kf = *(const f16x8*)(kb + (ks * 4 + jt) * 1024 + l * 16);
        sacc[0][jt] = MFMA16(kf, qf[0][ks], sacc[0][jt]);
        sacc[1][jt] = MFMA16(kf, qf[1][ks], sacc[1][jt]);
      }
    }
    __builtin_amdgcn_s_setprio(0);

    // ---- P = 2^S raw, packed to bf16 (lane-local; pi-V ordering)
    short8 pa[2][2];
#pragma unroll
    for (int s = 0; s < 2; ++s) {
      float rsum = 0.f;
#pragma unroll
      for (int ks2 = 0; ks2 < 2; ++ks2) {
        float pe[8];
#pragma unroll
        for (int u = 0; u < 2; ++u)
#pragma unroll
          for (int r4 = 0; r4 < 4; ++r4) {
            float pv = __builtin_amdgcn_exp2f(sacc[s][ks2 * 2 + u][r4]);
            rsum += pv;
            pe[u * 4 + r4] = pv;
          }
        union { unsigned int w2[4]; short8 v; } pk;
#pragma unroll
        for (int h2 = 0; h2 < 4; ++h2)
          pk.w2[h2] = pk_bf16(pe[h2 * 2], pe[h2 * 2 + 1]);
        pa[s][ks2] = pk.v;
      }
      ell[s] += rsum;
    }

    // ---- PV (bf16): B = pi-permuted V fragments from LDS
    __builtin_amdgcn_s_setprio(1);
#pragma unroll
    for (int ks2 = 0; ks2 < 2; ++ks2) {
#pragma unroll
      for (int nt = 0; nt < 8; ++nt) {
        short8 vbf = *(const short8*)(vb + (ks2 * 8 + nt) * 1024 + l * 16);
        o[0][nt] = MFMABF(pa[0][ks2], vbf, o[0][nt]);
        o[1][nt] = MFMABF(pa[1][ks2], vbf, o[1][nt]);
      }
    }
    __builtin_amdgcn_s_setprio(0);
  };

  const int ng = (nloc + 1) >> 1;
  stage_group(0);
  for (int g = 0; g < ng; ++g) {
    WAIT0;             // own gl16s of group g complete
    __syncthreads();   // all waves' LDS writes visible; buffer handoff

    compute(j0 + 2 * g, smem + KA_OFF, smem + VA_OFF);
    if (2 * g + 1 < nloc)
      compute(j0 + 2 * g + 1, smem + KB_OFF, smem + VB_OFF);

    __syncthreads();   // everyone done reading group g
    if (g + 1 < ng) stage_group(g + 1);
  }

  // finalize per-row sums across lg lanes (once per chunk)
#pragma unroll
  for (int s = 0; s < 2; ++s) {
    ell[s] += __shfl_xor(ell[s], 16);
    ell[s] += __shfl_xor(ell[s], 32);
  }

  // normalize o by per-row 1/ell so the f16 PART store stays in range;
  // broadcast rinv from q-row lanes (ll) to o-row layout (lg*4+r)
  float sb[2][4];
#pragma unroll
  for (int s = 0; s < 2; ++s) {
    float rinv = 1.f / ell[s];
#pragma unroll
    for (int r4 = 0; r4 < 4; ++r4) sb[s][r4] = __shfl(rinv, lg * 4 + r4);
  }

  // partial store, coalesced 16B/lane: [qh][slot=s*4+g][lane][16B]
  char* pb = PART + ((size_t)((pair * CHUNKS + ck) * 2 + half)) * PART_STRIDE;
#pragma unroll
  for (int s = 0; s < 2; ++s)
#pragma unroll
    for (int g = 0; g < 4; ++g) {
      f16x8 hh;
#pragma unroll
      for (int r4 = 0; r4 < 4; ++r4) {
        hh[r4] = (f16)(o[s][2 * g][r4] * sb[s][r4]);
        hh[4 + r4] = (f16)(o[s][2 * g + 1][r4] * sb[s][r4]);
      }
      *(f16x8*)(pb + qh * 8192 + ((s * 4 + g) * 64 + l) * 16) = hh;
    }
  if (lg == 0) {
#pragma unroll
    for (int s = 0; s < 2; ++s)
      *(float2*)(pb + 16384 + (qh * 32 + s * 16 + ll) * 8) =
          make_float2(0.f, ell[s]);
  }
}

// ---------------------------------------------------------------------------
// Merge: weighted sum of chunk partials (w_k = ell_k, raw-2^S scale) +
// out-of-band term with weight 1 per entry. Split by d-quarter: grid 1024,
// wg = (pair, half, dh2); each wg reads slots {sub*4 + dh2} only and
// writes cols [dh2*32, dh2*32+32).
__global__ __launch_bounds__(256) void merge_kernel(
    const char* __restrict__ PART, const float* __restrict__ BS,
    float* __restrict__ Out) {
  __shared__ float VoutS[DIM];
  __shared__ float mlS[CHUNKS][64][2];

  const int id = blockIdx.x;
  const int lin = (id & 7) * 128 + (id >> 3);  // XCD-contiguous pairs
  const int pair = lin >> 3;
  const int half = (lin >> 2) & 1;
  const int dh2 = lin & 3;
  const int b = pair >> 5;
  const int ib = (pair & 31) * 2 + half;
  const int t = threadIdx.x;
  const int l = t & 63, lg = (t >> 4) & 3, ll = t & 15;
  const int sub = (t >> 6) & 1, qh = t >> 7;

  const int jlo = max(0, ib - WBAND);
  const int jhi = min(NB, ib + WBAND);
  const float cnt_out = (float)(SEQ - (jhi - jlo) * 64);

  if (t < DIM) {
    float s = 0.f;
    for (int j = 0; j < jlo; ++j) s += BS[(b * NB + j) * DIM + t];
    for (int j = jhi; j < NB; ++j) s += BS[(b * NB + j) * DIM + t];
    VoutS[t] = s;
  }

  const size_t pb0 = ((size_t)(pair * CHUNKS * 2 + half)) * PART_STRIDE;
  for (int i = t; i < CHUNKS * 64; i += 256) {
    int k = i >> 6, row = i & 63;
    *(float2*)&mlS[k][row][0] = *(const float2*)(
        PART + pb0 + (size_t)k * 2 * PART_STRIDE + 16384 + row * 8);
  }
  __syncthreads();

  float aw[4][CHUNKS], inv[4];
#pragma unroll
  for (int r = 0; r < 4; ++r) {
    int row = qh * 32 + sub * 16 + lg * 4 + r;
    float den = cnt_out;
#pragma unroll
    for (int k = 0; k < CHUNKS; ++k) {
      aw[r][k] = mlS[k][row][1];
      den += aw[r][k];
    }
    inv[r] = 1.f / den;
  }

  float acc[2][4];
#pragma unroll
  for (int n2 = 0; n2 < 2; ++n2)
#pragma unroll
    for (int r = 0; r < 4; ++r) acc[n2][r] = 0.f;

  for (int k = 0; k < CHUNKS; ++k) {
    const char* oc = PART + pb0 + (size_t)k * 2 * PART_STRIDE + qh * 8192;
    int slot = sub * 4 + dh2;          // covers nt = 2*dh2, 2*dh2+1
    f16x8 h = *(const f16x8*)(oc + (slot * 64 + l) * 16);
#pragma unroll
    for (int r = 0; r < 4; ++r) {
      acc[0][r] += aw[r][k] * (float)h[r];
      acc[1][r] += aw[r][k] * (float)h[4 + r];
    }
  }

  const int q0 = ib * 64;
#pragma unroll
  for (int n2 = 0; n2 < 2; ++n2) {
    int nt = dh2 * 2 + n2;
    int col = nt * 16 + ll;
    float vout = VoutS[col];
#pragma unroll
    for (int r = 0; r < 4; ++r) {
      int row = qh * 32 + sub * 16 + lg * 4 + r;
      Out[((size_t)(b * SEQ + q0 + row)) * DIM + col] =
          (acc[n2][r] + vout) * inv[r];
    }
  }
}

// ---------------------------------------------------------------------------
extern "C" void kernel_launch(void* const* d_in, const int* in_sizes, int n_in,
                              void* d_out, int out_size, void* d_ws, size_t ws_size,
                              hipStream_t stream) {
  const float* Q = (const float*)d_in[0];
  const float* K = (const float*)d_in[1];
  const float* V = (const float*)d_in[2];
  float* Out = (float*)d_out;

  char* ws = (char*)d_ws;
  f16* KF = (f16*)ws;                                   // 4 MB
  unsigned short* VF = (unsigned short*)(ws + (size_t)BATCH * NB * TILE);  // 4 MB
  float* BS = (float*)(ws + 2 * (size_t)BATCH * NB * TILE);  // 128 KB
  char* PART = ws + 2 * (size_t)BATCH * NB * TILE + (size_t)BATCH * NB * DIM * 4;

  convert_kernel<<<dim3(BATCH * NB * 4), 256, 0, stream>>>(K, V, KF, VF, BS);
  attn_kernel<<<dim3(BATCH * NB / 2 * CHUNKS), 256, 0, stream>>>(Q, KF, VF, PART);
  merge_kernel<<<dim3(BATCH * NB * 4), 256, 0, stream>>>(PART, BS, Out);
}